// Round 1
// baseline (1661.362 us; speedup 1.0000x reference)
//
#include <hip/hip_runtime.h>
#include <cstdint>
#include <cstddef>

#define NUSER 50000
#define NITEM 40000
#define NNODE 90000
#define NE    1000000
#define DIM   64

// ---------------- workspace layout (float element offsets) ----------------
constexpr size_t O_XV   = 0;          // [90000*64] concat(pref_v, feat_v)
constexpr size_t O_XT   = 5760000;    // [90000*64]
constexpr size_t O_X0   = 11520000;   // [90000*64] l2norm(id_embedding)
constexpr size_t O_EV   = 17280000;   // [1M] exp(Lv) per CSR slot
constexpr size_t O_ET   = 18280000;   // [1M]
constexpr size_t O_WE   = 19280000;   // [1M] edge weight for egcn
constexpr size_t O_SV   = 20280000;   // [90000] softmax denom v
constexpr size_t O_STT  = 20370000;   // [90000] softmax denom t
constexpr size_t O_DEG  = 20460000;   // int [90000]
constexpr size_t O_RP   = 20550000;   // int [90001] row_ptr
constexpr size_t O_FILL = 20650000;   // int [90000]
constexpr size_t O_SRC  = 20750000;   // int [1M] src per CSR slot
constexpr size_t O_BSUM = 21750000;   // int [512]
constexpr size_t O_BOFF = 21751000;   // int [512]
constexpr size_t O_H1   = 0;          // aliases XV (xv dead after gat_final)

__device__ __forceinline__ float wsum(float v) {
#pragma unroll
  for (int off = 32; off > 0; off >>= 1) v += __shfl_xor(v, off, 64);
  return v;
}
__device__ __forceinline__ float leaky(float x) { return x >= 0.f ? x : 0.01f * x; }

// ---------------- CSR construction ----------------
__global__ void deg_count_kernel(const int* __restrict__ ei, int* __restrict__ deg) {
  int e = blockIdx.x * 256 + threadIdx.x;
  if (e >= NE) return;
  atomicAdd(&deg[ei[NE + e]], 1);
}

__global__ void block_sum_kernel(const int* __restrict__ deg, int* __restrict__ bsum) {
  __shared__ int sd[4];
  int i = blockIdx.x * 256 + threadIdx.x;
  int v = (i < NNODE) ? deg[i] : 0;
#pragma unroll
  for (int off = 32; off > 0; off >>= 1) v += __shfl_xor(v, off, 64);
  if ((threadIdx.x & 63) == 0) sd[threadIdx.x >> 6] = v;
  __syncthreads();
  if (threadIdx.x == 0) bsum[blockIdx.x] = sd[0] + sd[1] + sd[2] + sd[3];
}

__global__ void scan_bsum_kernel(const int* __restrict__ bsum, int* __restrict__ boff, int nb) {
  __shared__ int s[512];
  int t = threadIdx.x;
  int v = (t < nb) ? bsum[t] : 0;
  s[t] = v;
  __syncthreads();
  for (int off = 1; off < 512; off <<= 1) {
    int x = (t >= off) ? s[t - off] : 0;
    __syncthreads();
    s[t] += x;
    __syncthreads();
  }
  if (t < nb) boff[t] = s[t] - v;  // exclusive
}

__global__ void scan_final_kernel(const int* __restrict__ deg, const int* __restrict__ boff,
                                  int* __restrict__ row_ptr, int* __restrict__ fill) {
  __shared__ int s[256];
  int t = threadIdx.x;
  int i = blockIdx.x * 256 + t;
  int v = (i < NNODE) ? deg[i] : 0;
  s[t] = v;
  __syncthreads();
  for (int off = 1; off < 256; off <<= 1) {
    int x = (t >= off) ? s[t - off] : 0;
    __syncthreads();
    s[t] += x;
    __syncthreads();
  }
  int incl = s[t];
  int base = boff[blockIdx.x];
  if (i < NNODE) {
    row_ptr[i] = base + incl - v;
    fill[i] = base + incl - v;
    if (i == NNODE - 1) row_ptr[NNODE] = base + incl;
  }
}

__global__ void csr_fill_kernel(const int* __restrict__ ei, int* __restrict__ fill,
                                int* __restrict__ srcs) {
  int e = blockIdx.x * 256 + threadIdx.x;
  if (e >= NE) return;
  int s = ei[e], d = ei[NE + e];
  int slot = atomicAdd(&fill[d], 1);
  srcs[slot] = s;
}

// ---------------- GEMM: out = leaky(A[M,K] @ W[K,64] + b), M=40000 ----------------
__global__ __launch_bounds__(256) void gemm_feat_kernel(const float* __restrict__ A,
                                                        const float* __restrict__ W,
                                                        const float* __restrict__ bias,
                                                        float* __restrict__ out, int K) {
  __shared__ float As[32][68];
  __shared__ float Bs[32][68];
  int tid = threadIdx.x;
  int tx = tid & 15, ty = tid >> 4;
  int m0 = blockIdx.x * 64;
  float acc[4][4] = {};
  int lr = tid >> 3;         // 0..31
  int lk = (tid & 7) * 4;    // 0..28
  int wk = tid >> 4;         // 0..15
  int wc = (tid & 15) * 4;   // 0..60

  for (int k0 = 0; k0 < K; k0 += 32) {
#pragma unroll
    for (int p = 0; p < 2; ++p) {
      int row = lr + p * 32;
      float4 a = *(const float4*)&A[(size_t)(m0 + row) * K + k0 + lk];
      As[lk + 0][row] = a.x; As[lk + 1][row] = a.y;
      As[lk + 2][row] = a.z; As[lk + 3][row] = a.w;
    }
#pragma unroll
    for (int p = 0; p < 2; ++p) {
      int kk = wk + p * 16;
      *(float4*)&Bs[kk][wc] = *(const float4*)&W[(size_t)(k0 + kk) * 64 + wc];
    }
    __syncthreads();
#pragma unroll
    for (int kk = 0; kk < 32; ++kk) {
      float4 a4 = *(const float4*)&As[kk][ty * 4];
      float4 b4 = *(const float4*)&Bs[kk][tx * 4];
      float av[4] = {a4.x, a4.y, a4.z, a4.w};
      float bv[4] = {b4.x, b4.y, b4.z, b4.w};
#pragma unroll
      for (int i = 0; i < 4; ++i)
#pragma unroll
        for (int j = 0; j < 4; ++j) acc[i][j] = fmaf(av[i], bv[j], acc[i][j]);
    }
    __syncthreads();
  }
#pragma unroll
  for (int i = 0; i < 4; ++i) {
    int row = m0 + ty * 4 + i;
    float4 o;
    o.x = leaky(acc[i][0] + bias[tx * 4 + 0]);
    o.y = leaky(acc[i][1] + bias[tx * 4 + 1]);
    o.z = leaky(acc[i][2] + bias[tx * 4 + 2]);
    o.w = leaky(acc[i][3] + bias[tx * 4 + 3]);
    *(float4*)&out[(size_t)row * 64 + tx * 4] = o;
  }
}

// ---------------- row-wise l2norm (wave per row) ----------------
__global__ __launch_bounds__(256) void l2norm_rows_kernel(const float* __restrict__ in,
                                                          float* __restrict__ out, int nrows) {
  int wid = (blockIdx.x * 256 + threadIdx.x) >> 6;
  int lane = threadIdx.x & 63;
  if (wid >= nrows) return;
  float v = in[(size_t)wid * 64 + lane];
  float ss = wsum(v * v);
  out[(size_t)wid * 64 + lane] = v / fmaxf(sqrtf(ss), 1e-12f);
}

// ---------------- routing: pref = l2norm(pref + softmax-agg(features)) ----------------
__global__ __launch_bounds__(256) void routing_kernel(float* __restrict__ x,
                                                      const int* __restrict__ row_ptr,
                                                      const int* __restrict__ srcs) {
  int wid = (blockIdx.x * 256 + threadIdx.x) >> 6;
  int lane = threadIdx.x & 63;
  if (wid >= NUSER) return;
  float p = x[(size_t)wid * 64 + lane];
  int jb = row_ptr[wid], je = row_ptr[wid + 1];
  float S = 0.f, acc = 0.f;
  for (int j = jb; j < je; ++j) {
    int s = srcs[j];
    float f = x[(size_t)s * 64 + lane];
    float d = wsum(p * f);        // logit in [-1,1], no max-shift needed
    float e = __expf(d);
    S += e;
    acc += e * f;
  }
  if (je > jb) p += acc / S;
  float ss = wsum(p * p);
  x[(size_t)wid * 64 + lane] = p / fmaxf(sqrtf(ss), 1e-12f);
}

// ---------------- final GAT: rep = x + leaky(softmax-agg); stash e, S ----------------
__global__ __launch_bounds__(256) void gat_final_kernel(const float* __restrict__ x,
                                                        const int* __restrict__ row_ptr,
                                                        const int* __restrict__ srcs,
                                                        float* __restrict__ eOut,
                                                        float* __restrict__ Sout,
                                                        float* __restrict__ out, int col_off) {
  int wid = (blockIdx.x * 256 + threadIdx.x) >> 6;
  int lane = threadIdx.x & 63;
  if (wid >= NNODE) return;
  float xn = x[(size_t)wid * 64 + lane];
  int jb = row_ptr[wid], je = row_ptr[wid + 1];
  float S = 0.f, acc = 0.f;
  for (int j = jb; j < je; ++j) {
    int s = srcs[j];
    float f = x[(size_t)s * 64 + lane];
    float d = wsum(xn * f);
    float e = __expf(d);
    if (lane == 0) eOut[j] = e;
    S += e;
    acc += e * f;
  }
  if (lane == 0) Sout[wid] = S;
  float xh = (je > jb) ? acc / S : 0.f;
  out[(size_t)wid * 192 + col_off + lane] = xn + leaky(xh);
}

// ---------------- egcn hop 1: weights + weighted mean of x0 ----------------
__global__ __launch_bounds__(256) void egcn_h1_kernel(const float* __restrict__ x0,
                                                      const int* __restrict__ row_ptr,
                                                      const int* __restrict__ srcs,
                                                      const float* __restrict__ eV,
                                                      const float* __restrict__ eT,
                                                      const float* __restrict__ SV,
                                                      const float* __restrict__ ST,
                                                      const float* __restrict__ conf,
                                                      float* __restrict__ wE,
                                                      float* __restrict__ h1) {
  int wid = (blockIdx.x * 256 + threadIdx.x) >> 6;
  int lane = threadIdx.x & 63;
  if (wid >= NNODE) return;
  int jb = row_ptr[wid], je = row_ptr[wid + 1];
  float rv = 0.f, rt = 0.f;
  if (je > jb) {
    rv = 0.5f / SV[wid];   // alpha_v = e/(2*S_v)
    rt = 0.5f / ST[wid];
  }
  float acc = 0.f;
  for (int j = jb; j < je; ++j) {
    int s = srcs[j];
    float w = fmaxf(fmaxf(eV[j] * rv * conf[2 * s], eT[j] * rt * conf[2 * s + 1]), 0.f);
    if (lane == 0) wE[j] = w;
    acc += x0[(size_t)s * 64 + lane] * w;
  }
  float h = (je > jb) ? leaky(acc / (float)(je - jb)) : 0.f;
  h1[(size_t)wid * 64 + lane] = h;
}

// ---------------- egcn hop 2 + final id_rep write ----------------
__global__ __launch_bounds__(256) void egcn_h2_kernel(const float* __restrict__ x0,
                                                      const float* __restrict__ h1,
                                                      const int* __restrict__ row_ptr,
                                                      const int* __restrict__ srcs,
                                                      const float* __restrict__ wE,
                                                      float* __restrict__ out) {
  int wid = (blockIdx.x * 256 + threadIdx.x) >> 6;
  int lane = threadIdx.x & 63;
  if (wid >= NNODE) return;
  int jb = row_ptr[wid], je = row_ptr[wid + 1];
  float acc = 0.f;
  for (int j = jb; j < je; ++j) {
    acc += h1[(size_t)srcs[j] * 64 + lane] * wE[j];
  }
  float h2 = (je > jb) ? leaky(acc / (float)(je - jb)) : 0.f;
  out[(size_t)wid * 192 + lane] =
      x0[(size_t)wid * 64 + lane] + h1[(size_t)wid * 64 + lane] + h2;
}

// ---------------- launcher ----------------
extern "C" void kernel_launch(void* const* d_in, const int* in_sizes, int n_in,
                              void* d_out, int out_size, void* d_ws, size_t ws_size,
                              hipStream_t stream) {
  const int* ei = (const int*)d_in[0];
  const float* v_feat = (const float*)d_in[1];
  const float* t_feat = (const float*)d_in[2];
  const float* pref_v = (const float*)d_in[3];
  const float* pref_t = (const float*)d_in[4];
  const float* W_v = (const float*)d_in[5];
  const float* b_v = (const float*)d_in[6];
  const float* W_t = (const float*)d_in[7];
  const float* b_t = (const float*)d_in[8];
  const float* id_emb = (const float*)d_in[9];
  const float* conf = (const float*)d_in[10];
  float* out = (float*)d_out;

  float* ws = (float*)d_ws;
  float* xv = ws + O_XV;
  float* xt = ws + O_XT;
  float* x0 = ws + O_X0;
  float* eV = ws + O_EV;
  float* eT = ws + O_ET;
  float* wE = ws + O_WE;
  float* SV = ws + O_SV;
  float* ST = ws + O_STT;
  int* deg = (int*)(ws + O_DEG);
  int* row_ptr = (int*)(ws + O_RP);
  int* fill = (int*)(ws + O_FILL);
  int* srcs = (int*)(ws + O_SRC);
  int* bsum = (int*)(ws + O_BSUM);
  int* boff = (int*)(ws + O_BOFF);
  float* h1 = ws + O_H1;  // aliases xv: safe, xv is dead after gat_final launches

  const int NB = (NNODE + 255) / 256;  // 352

  // CSR build
  hipMemsetAsync(deg, 0, NNODE * sizeof(int), stream);
  deg_count_kernel<<<(NE + 255) / 256, 256, 0, stream>>>(ei, deg);
  block_sum_kernel<<<NB, 256, 0, stream>>>(deg, bsum);
  scan_bsum_kernel<<<1, 512, 0, stream>>>(bsum, boff, NB);
  scan_final_kernel<<<NB, 256, 0, stream>>>(deg, boff, row_ptr, fill);
  csr_fill_kernel<<<(NE + 255) / 256, 256, 0, stream>>>(ei, fill, srcs);

  // features = leaky(feat @ W + b)  (pre-norm), into x[50000:]
  gemm_feat_kernel<<<NITEM / 64, 256, 0, stream>>>(v_feat, W_v, b_v, xv + (size_t)NUSER * 64, 2048);
  gemm_feat_kernel<<<NITEM / 64, 256, 0, stream>>>(t_feat, W_t, b_t, xt + (size_t)NUSER * 64, 384);

  // l2norms: features in-place, prefs into x[:50000], id_emb into x0
  l2norm_rows_kernel<<<NITEM / 4, 256, 0, stream>>>(xv + (size_t)NUSER * 64, xv + (size_t)NUSER * 64, NITEM);
  l2norm_rows_kernel<<<NITEM / 4, 256, 0, stream>>>(xt + (size_t)NUSER * 64, xt + (size_t)NUSER * 64, NITEM);
  l2norm_rows_kernel<<<NUSER / 4, 256, 0, stream>>>(pref_v, xv, NUSER);
  l2norm_rows_kernel<<<NUSER / 4, 256, 0, stream>>>(pref_t, xt, NUSER);
  l2norm_rows_kernel<<<NNODE / 4, 256, 0, stream>>>(id_emb, x0, NNODE);

  // routing (3 iters per modality; user rows of the full CSR are exactly it->u edges)
  for (int it = 0; it < 3; ++it)
    routing_kernel<<<NUSER / 4, 256, 0, stream>>>(xv, row_ptr, srcs);
  for (int it = 0; it < 3; ++it)
    routing_kernel<<<NUSER / 4, 256, 0, stream>>>(xt, row_ptr, srcs);

  // final GAT per modality -> out[:,64:128] and out[:,128:192], stash e & S
  gat_final_kernel<<<NNODE / 4, 256, 0, stream>>>(xv, row_ptr, srcs, eV, SV, out, 64);
  gat_final_kernel<<<NNODE / 4, 256, 0, stream>>>(xt, row_ptr, srcs, eT, ST, out, 128);

  // egcn (h1 aliases xv, which is no longer needed)
  egcn_h1_kernel<<<NNODE / 4, 256, 0, stream>>>(x0, row_ptr, srcs, eV, eT, SV, ST, conf, wE, h1);
  egcn_h2_kernel<<<NNODE / 4, 256, 0, stream>>>(x0, h1, row_ptr, srcs, wE, out);
}

// Round 2
// 1058.377 us; speedup vs baseline: 1.5697x; 1.5697x over previous
//
#include <hip/hip_runtime.h>
#include <hip/hip_bf16.h>
#include <cstdint>
#include <cstddef>

#define NUSER 50000
#define NITEM 40000
#define NNODE 90000
#define NE    1000000
#define DIM   64

typedef __attribute__((ext_vector_type(8))) short short8;
typedef __attribute__((ext_vector_type(4))) float f32x4;

// ---------------- workspace layout (float element offsets) ----------------
constexpr size_t O_XV   = 0;          // [90000*64]
constexpr size_t O_XT   = 5760000;    // [90000*64]
constexpr size_t O_X0   = 11520000;   // [90000*64]; first reused as split-W storage
constexpr size_t O_EV   = 17280000;   // [1M]
constexpr size_t O_ET   = 18280000;   // [1M]
constexpr size_t O_WE   = 19280000;   // [1M]
constexpr size_t O_SV   = 20280000;   // [90000]
constexpr size_t O_STT  = 20370000;   // [90000]
constexpr size_t O_DEG  = 20460000;   // int [90000]
constexpr size_t O_RP   = 20550000;   // int [90001]
constexpr size_t O_FILL = 20650000;   // int [90000]
constexpr size_t O_SRC  = 20750000;   // int [1M]
constexpr size_t O_BSUM = 21750000;   // int [512]
constexpr size_t O_BOFF = 21751000;   // int [512]
constexpr size_t O_H1   = 0;          // aliases XV (xv dead after gat_final)
// split-W (bf16/short) offsets within X0 region, in shorts:
constexpr size_t SW_VHI = 0;
constexpr size_t SW_VLO = 131072;     // 2048*64
constexpr size_t SW_THI = 262144;
constexpr size_t SW_TLO = 286720;     // +384*64

__device__ __forceinline__ float leaky(float x) { return x >= 0.f ? x : 0.01f * x; }

__device__ __forceinline__ short f2bf(float x) {
  __hip_bfloat16 h = __float2bfloat16(x);
  return *reinterpret_cast<short*>(&h);
}
__device__ __forceinline__ float bf2f(short s) {
  __hip_bfloat16 h;
  *reinterpret_cast<short*>(&h) = s;
  return __bfloat162float(h);
}

// ---------------- CSR construction ----------------
__global__ void deg_count_kernel(const int* __restrict__ ei, int* __restrict__ deg) {
  int e = blockIdx.x * 256 + threadIdx.x;
  if (e >= NE) return;
  atomicAdd(&deg[ei[NE + e]], 1);
}

__global__ void block_sum_kernel(const int* __restrict__ deg, int* __restrict__ bsum) {
  __shared__ int sd[4];
  int i = blockIdx.x * 256 + threadIdx.x;
  int v = (i < NNODE) ? deg[i] : 0;
#pragma unroll
  for (int off = 32; off > 0; off >>= 1) v += __shfl_xor(v, off, 64);
  if ((threadIdx.x & 63) == 0) sd[threadIdx.x >> 6] = v;
  __syncthreads();
  if (threadIdx.x == 0) bsum[blockIdx.x] = sd[0] + sd[1] + sd[2] + sd[3];
}

__global__ void scan_bsum_kernel(const int* __restrict__ bsum, int* __restrict__ boff, int nb) {
  __shared__ int s[512];
  int t = threadIdx.x;
  int v = (t < nb) ? bsum[t] : 0;
  s[t] = v;
  __syncthreads();
  for (int off = 1; off < 512; off <<= 1) {
    int x = (t >= off) ? s[t - off] : 0;
    __syncthreads();
    s[t] += x;
    __syncthreads();
  }
  if (t < nb) boff[t] = s[t] - v;
}

__global__ void scan_final_kernel(const int* __restrict__ deg, const int* __restrict__ boff,
                                  int* __restrict__ row_ptr, int* __restrict__ fill) {
  __shared__ int s[256];
  int t = threadIdx.x;
  int i = blockIdx.x * 256 + t;
  int v = (i < NNODE) ? deg[i] : 0;
  s[t] = v;
  __syncthreads();
  for (int off = 1; off < 256; off <<= 1) {
    int x = (t >= off) ? s[t - off] : 0;
    __syncthreads();
    s[t] += x;
    __syncthreads();
  }
  int incl = s[t];
  int base = boff[blockIdx.x];
  if (i < NNODE) {
    row_ptr[i] = base + incl - v;
    fill[i] = base + incl - v;
    if (i == NNODE - 1) row_ptr[NNODE] = base + incl;
  }
}

__global__ void csr_fill_kernel(const int* __restrict__ ei, int* __restrict__ fill,
                                int* __restrict__ srcs) {
  int e = blockIdx.x * 256 + threadIdx.x;
  if (e >= NE) return;
  int s = ei[e], d = ei[NE + e];
  int slot = atomicAdd(&fill[d], 1);
  srcs[slot] = s;
}

// ---------------- W split: fp32 -> bf16 hi/lo in MFMA-fragment-linear layout --------
// dst flat index = (((kt*4 + nt)*4 + q)*16 + sl)*8 + j  <=>  W[kt*32+q*8+j][nt*16+sl]
__global__ void wsplit_kernel(const float* __restrict__ W, short* __restrict__ hi,
                              short* __restrict__ lo, int nelem) {
  int t = blockIdx.x * 256 + threadIdx.x;
  if (t >= nelem) return;
  int j = t & 7, sl = (t >> 3) & 15, q = (t >> 7) & 3, nt = (t >> 9) & 3, kt = t >> 11;
  int k = kt * 32 + q * 8 + j, n = nt * 16 + sl;
  float x = W[k * 64 + n];
  short h = f2bf(x);
  hi[t] = h;
  lo[t] = f2bf(x - bf2f(h));
}

// ---------------- GEMM: out = l2norm_row(leaky(A[M,K]@W[K,64]+b)), split-bf16 MFMA --
__global__ __launch_bounds__(256) void gemm_mfma_kernel(const float* __restrict__ A,
                                                        const short* __restrict__ Whi,
                                                        const short* __restrict__ Wlo,
                                                        const float* __restrict__ bias,
                                                        float* __restrict__ out, int K) {
  __shared__ short Bsh[8192];  // 4 kt * 4 nt * 512, frag-linear
  __shared__ short Bsl[8192];
  int tid = threadIdx.x;
  int w = tid >> 6, lane = tid & 63, q = lane >> 4, sl = lane & 15;
  int m0 = blockIdx.x * 64;
  const float* arow = A + (size_t)(m0 + w * 16 + sl) * K;
  f32x4 acc[4] = {{0.f, 0.f, 0.f, 0.f}, {0.f, 0.f, 0.f, 0.f},
                  {0.f, 0.f, 0.f, 0.f}, {0.f, 0.f, 0.f, 0.f}};
  int nchunk = K >> 7;  // K multiple of 128
  for (int c = 0; c < nchunk; ++c) {
    __syncthreads();
    const float4* srch = (const float4*)(Whi + (size_t)c * 8192);
    const float4* srcl = (const float4*)(Wlo + (size_t)c * 8192);
    float4* dsth = (float4*)Bsh;
    float4* dstl = (float4*)Bsl;
#pragma unroll
    for (int r = 0; r < 4; ++r) {
      dsth[r * 256 + tid] = srch[r * 256 + tid];
      dstl[r * 256 + tid] = srcl[r * 256 + tid];
    }
    __syncthreads();
#pragma unroll
    for (int kt = 0; kt < 4; ++kt) {
      int k = c * 128 + kt * 32 + q * 8;
      float4 a0 = *(const float4*)&arow[k];
      float4 a1 = *(const float4*)&arow[k + 4];
      float av[8] = {a0.x, a0.y, a0.z, a0.w, a1.x, a1.y, a1.z, a1.w};
      short8 ah, al;
#pragma unroll
      for (int j = 0; j < 8; ++j) {
        short h = f2bf(av[j]);
        ah[j] = h;
        al[j] = f2bf(av[j] - bf2f(h));
      }
#pragma unroll
      for (int nt = 0; nt < 4; ++nt) {
        short8 bh = *(short8*)&Bsh[(kt * 4 + nt) * 512 + lane * 8];
        short8 bl = *(short8*)&Bsl[(kt * 4 + nt) * 512 + lane * 8];
        acc[nt] = __builtin_amdgcn_mfma_f32_16x16x32_bf16(ah, bh, acc[nt], 0, 0, 0);
        acc[nt] = __builtin_amdgcn_mfma_f32_16x16x32_bf16(ah, bl, acc[nt], 0, 0, 0);
        acc[nt] = __builtin_amdgcn_mfma_f32_16x16x32_bf16(al, bh, acc[nt], 0, 0, 0);
      }
    }
  }
  // epilogue: bias + leaky + row l2norm. C/D: col=lane&15 (within nt), row=q*4+reg
  float bnt[4];
#pragma unroll
  for (int nt = 0; nt < 4; ++nt) bnt[nt] = bias[nt * 16 + sl];
  float v[4][4];
#pragma unroll
  for (int nt = 0; nt < 4; ++nt)
#pragma unroll
    for (int i = 0; i < 4; ++i) v[nt][i] = leaky(acc[nt][i] + bnt[nt]);
#pragma unroll
  for (int i = 0; i < 4; ++i) {
    float ss = v[0][i] * v[0][i] + v[1][i] * v[1][i] + v[2][i] * v[2][i] + v[3][i] * v[3][i];
    ss += __shfl_xor(ss, 1);
    ss += __shfl_xor(ss, 2);
    ss += __shfl_xor(ss, 4);
    ss += __shfl_xor(ss, 8);
    float rinv = 1.f / fmaxf(sqrtf(ss), 1e-12f);
    int row = m0 + w * 16 + q * 4 + i;
#pragma unroll
    for (int nt = 0; nt < 4; ++nt)
      out[(size_t)row * 64 + nt * 16 + sl] = v[nt][i] * rinv;
  }
}

// ---------------- fused l2norm: pref_v->xv, pref_t->xt, id->x0 (4 rows/wave) --------
__global__ __launch_bounds__(256) void l2norm_all_kernel(const float* __restrict__ pv,
                                                         const float* __restrict__ pt,
                                                         const float* __restrict__ id,
                                                         float* __restrict__ xv,
                                                         float* __restrict__ xt,
                                                         float* __restrict__ x0) {
  int wid = (blockIdx.x * 256 + threadIdx.x) >> 6;
  int lane = threadIdx.x & 63, sub = lane >> 4, sl = lane & 15;
  int r = wid * 4 + sub;  // 0..189999
  if (r >= 2 * NUSER + NNODE) return;
  const float* in;
  float* outp;
  int row;
  if (r < NUSER) { in = pv; outp = xv; row = r; }
  else if (r < 2 * NUSER) { in = pt; outp = xt; row = r - NUSER; }
  else { in = id; outp = x0; row = r - 2 * NUSER; }
  float4 v = *(const float4*)&in[(size_t)row * 64 + sl * 4];
  float ss = v.x * v.x + v.y * v.y + v.z * v.z + v.w * v.w;
  ss += __shfl_xor(ss, 1);
  ss += __shfl_xor(ss, 2);
  ss += __shfl_xor(ss, 4);
  ss += __shfl_xor(ss, 8);
  float rinv = 1.f / fmaxf(sqrtf(ss), 1e-12f);
  v.x *= rinv; v.y *= rinv; v.z *= rinv; v.w *= rinv;
  *(float4*)&outp[(size_t)row * 64 + sl * 4] = v;
}

// ---------------- routing (v+t fused): pref = l2norm(pref + softmax-agg) -----------
__global__ __launch_bounds__(256) void routing_kernel(float* __restrict__ xv,
                                                      float* __restrict__ xt,
                                                      const int* __restrict__ rp,
                                                      const int* __restrict__ srcs) {
  int wid = (blockIdx.x * 256 + threadIdx.x) >> 6;
  int lane = threadIdx.x & 63, sub = lane >> 4, sl = lane & 15;
  if (wid >= 2 * NUSER) return;
  float* x = (wid < NUSER) ? xv : xt;
  int row = (wid < NUSER) ? wid : wid - NUSER;
  float4 p = *(const float4*)&x[(size_t)row * 64 + sl * 4];
  int jb = rp[row], je = rp[row + 1];
  float S = 0.f;
  float4 acc = {0.f, 0.f, 0.f, 0.f};
  for (int j0 = jb; j0 < je; j0 += 4) {
    int j = j0 + sub;
    bool valid = j < je;
    int jj = valid ? j : jb;
    int s = srcs[jj];
    float4 f = *(const float4*)&x[(size_t)s * 64 + sl * 4];
    float d = p.x * f.x + p.y * f.y + p.z * f.z + p.w * f.w;
    d += __shfl_xor(d, 1);
    d += __shfl_xor(d, 2);
    d += __shfl_xor(d, 4);
    d += __shfl_xor(d, 8);
    float e = valid ? __expf(d) : 0.f;
    S += e;
    acc.x += e * f.x; acc.y += e * f.y; acc.z += e * f.z; acc.w += e * f.w;
  }
  S += __shfl_xor(S, 16); S += __shfl_xor(S, 32);
  acc.x += __shfl_xor(acc.x, 16); acc.x += __shfl_xor(acc.x, 32);
  acc.y += __shfl_xor(acc.y, 16); acc.y += __shfl_xor(acc.y, 32);
  acc.z += __shfl_xor(acc.z, 16); acc.z += __shfl_xor(acc.z, 32);
  acc.w += __shfl_xor(acc.w, 16); acc.w += __shfl_xor(acc.w, 32);
  if (je > jb) {
    float r = 1.f / S;
    p.x += acc.x * r; p.y += acc.y * r; p.z += acc.z * r; p.w += acc.w * r;
  }
  float ss = p.x * p.x + p.y * p.y + p.z * p.z + p.w * p.w;
  ss += __shfl_xor(ss, 1);
  ss += __shfl_xor(ss, 2);
  ss += __shfl_xor(ss, 4);
  ss += __shfl_xor(ss, 8);
  float rinv = 1.f / fmaxf(sqrtf(ss), 1e-12f);
  if (sub == 0) {
    float4 o = {p.x * rinv, p.y * rinv, p.z * rinv, p.w * rinv};
    *(float4*)&x[(size_t)row * 64 + sl * 4] = o;
  }
}

// ---------------- final GAT (v+t fused): out-col = x + leaky(agg); stash e,S --------
__global__ __launch_bounds__(256) void gat_final_kernel(const float* __restrict__ xv,
                                                        const float* __restrict__ xt,
                                                        const int* __restrict__ rp,
                                                        const int* __restrict__ srcs,
                                                        float* __restrict__ eV,
                                                        float* __restrict__ eT,
                                                        float* __restrict__ SV,
                                                        float* __restrict__ ST,
                                                        float* __restrict__ out) {
  int wid = (blockIdx.x * 256 + threadIdx.x) >> 6;
  int lane = threadIdx.x & 63, sub = lane >> 4, sl = lane & 15;
  if (wid >= 2 * NNODE) return;
  const float* x;
  float* eOut;
  float* Sout;
  int row, col;
  if (wid < NNODE) { x = xv; eOut = eV; Sout = SV; row = wid; col = 64; }
  else { x = xt; eOut = eT; Sout = ST; row = wid - NNODE; col = 128; }
  float4 xn = *(const float4*)&x[(size_t)row * 64 + sl * 4];
  int jb = rp[row], je = rp[row + 1];
  float S = 0.f;
  float4 acc = {0.f, 0.f, 0.f, 0.f};
  for (int j0 = jb; j0 < je; j0 += 4) {
    int j = j0 + sub;
    bool valid = j < je;
    int jj = valid ? j : jb;
    int s = srcs[jj];
    float4 f = *(const float4*)&x[(size_t)s * 64 + sl * 4];
    float d = xn.x * f.x + xn.y * f.y + xn.z * f.z + xn.w * f.w;
    d += __shfl_xor(d, 1);
    d += __shfl_xor(d, 2);
    d += __shfl_xor(d, 4);
    d += __shfl_xor(d, 8);
    float e = valid ? __expf(d) : 0.f;
    if (valid && sl == 0) eOut[j] = e;
    S += e;
    acc.x += e * f.x; acc.y += e * f.y; acc.z += e * f.z; acc.w += e * f.w;
  }
  S += __shfl_xor(S, 16); S += __shfl_xor(S, 32);
  acc.x += __shfl_xor(acc.x, 16); acc.x += __shfl_xor(acc.x, 32);
  acc.y += __shfl_xor(acc.y, 16); acc.y += __shfl_xor(acc.y, 32);
  acc.z += __shfl_xor(acc.z, 16); acc.z += __shfl_xor(acc.z, 32);
  acc.w += __shfl_xor(acc.w, 16); acc.w += __shfl_xor(acc.w, 32);
  if (lane == 0) Sout[row] = S;
  float4 o;
  if (je > jb) {
    float r = 1.f / S;
    o.x = xn.x + leaky(acc.x * r);
    o.y = xn.y + leaky(acc.y * r);
    o.z = xn.z + leaky(acc.z * r);
    o.w = xn.w + leaky(acc.w * r);
  } else {
    o = xn;
  }
  if (sub == 0) *(float4*)&out[(size_t)row * 192 + col + sl * 4] = o;
}

// ---------------- egcn hop 1: weights + weighted mean of x0 ------------------------
__global__ __launch_bounds__(256) void egcn_h1_kernel(const float* __restrict__ x0,
                                                      const int* __restrict__ rp,
                                                      const int* __restrict__ srcs,
                                                      const float* __restrict__ eV,
                                                      const float* __restrict__ eT,
                                                      const float* __restrict__ SV,
                                                      const float* __restrict__ ST,
                                                      const float* __restrict__ conf,
                                                      float* __restrict__ wE,
                                                      float* __restrict__ h1) {
  int wid = (blockIdx.x * 256 + threadIdx.x) >> 6;
  int lane = threadIdx.x & 63, sub = lane >> 4, sl = lane & 15;
  if (wid >= NNODE) return;
  int jb = rp[wid], je = rp[wid + 1];
  float rv = 0.f, rt = 0.f;
  if (je > jb) {
    rv = 0.5f / SV[wid];
    rt = 0.5f / ST[wid];
  }
  float4 acc = {0.f, 0.f, 0.f, 0.f};
  for (int j0 = jb; j0 < je; j0 += 4) {
    int j = j0 + sub;
    bool valid = j < je;
    int jj = valid ? j : jb;
    int s = srcs[jj];
    float w = fmaxf(fmaxf(eV[jj] * rv * conf[2 * s], eT[jj] * rt * conf[2 * s + 1]), 0.f);
    if (!valid) w = 0.f;
    if (valid && sl == 0) wE[j] = w;
    float4 f = *(const float4*)&x0[(size_t)s * 64 + sl * 4];
    acc.x += f.x * w; acc.y += f.y * w; acc.z += f.z * w; acc.w += f.w * w;
  }
  acc.x += __shfl_xor(acc.x, 16); acc.x += __shfl_xor(acc.x, 32);
  acc.y += __shfl_xor(acc.y, 16); acc.y += __shfl_xor(acc.y, 32);
  acc.z += __shfl_xor(acc.z, 16); acc.z += __shfl_xor(acc.z, 32);
  acc.w += __shfl_xor(acc.w, 16); acc.w += __shfl_xor(acc.w, 32);
  if (sub == 0) {
    float4 o = {0.f, 0.f, 0.f, 0.f};
    if (je > jb) {
      float r = 1.f / (float)(je - jb);
      o.x = leaky(acc.x * r); o.y = leaky(acc.y * r);
      o.z = leaky(acc.z * r); o.w = leaky(acc.w * r);
    }
    *(float4*)&h1[(size_t)wid * 64 + sl * 4] = o;
  }
}

// ---------------- egcn hop 2 + final id_rep write ----------------------------------
__global__ __launch_bounds__(256) void egcn_h2_kernel(const float* __restrict__ x0,
                                                      const float* __restrict__ h1,
                                                      const int* __restrict__ rp,
                                                      const int* __restrict__ srcs,
                                                      const float* __restrict__ wE,
                                                      float* __restrict__ out) {
  int wid = (blockIdx.x * 256 + threadIdx.x) >> 6;
  int lane = threadIdx.x & 63, sub = lane >> 4, sl = lane & 15;
  if (wid >= NNODE) return;
  int jb = rp[wid], je = rp[wid + 1];
  float4 acc = {0.f, 0.f, 0.f, 0.f};
  for (int j0 = jb; j0 < je; j0 += 4) {
    int j = j0 + sub;
    bool valid = j < je;
    int jj = valid ? j : jb;
    int s = srcs[jj];
    float w = valid ? wE[jj] : 0.f;
    float4 f = *(const float4*)&h1[(size_t)s * 64 + sl * 4];
    acc.x += f.x * w; acc.y += f.y * w; acc.z += f.z * w; acc.w += f.w * w;
  }
  acc.x += __shfl_xor(acc.x, 16); acc.x += __shfl_xor(acc.x, 32);
  acc.y += __shfl_xor(acc.y, 16); acc.y += __shfl_xor(acc.y, 32);
  acc.z += __shfl_xor(acc.z, 16); acc.z += __shfl_xor(acc.z, 32);
  acc.w += __shfl_xor(acc.w, 16); acc.w += __shfl_xor(acc.w, 32);
  if (sub == 0) {
    float4 h2 = {0.f, 0.f, 0.f, 0.f};
    if (je > jb) {
      float r = 1.f / (float)(je - jb);
      h2.x = leaky(acc.x * r); h2.y = leaky(acc.y * r);
      h2.z = leaky(acc.z * r); h2.w = leaky(acc.w * r);
    }
    float4 a = *(const float4*)&x0[(size_t)wid * 64 + sl * 4];
    float4 b = *(const float4*)&h1[(size_t)wid * 64 + sl * 4];
    float4 o = {a.x + b.x + h2.x, a.y + b.y + h2.y, a.z + b.z + h2.z, a.w + b.w + h2.w};
    *(float4*)&out[(size_t)wid * 192 + sl * 4] = o;
  }
}

// ---------------- launcher ----------------
extern "C" void kernel_launch(void* const* d_in, const int* in_sizes, int n_in,
                              void* d_out, int out_size, void* d_ws, size_t ws_size,
                              hipStream_t stream) {
  const int* ei = (const int*)d_in[0];
  const float* v_feat = (const float*)d_in[1];
  const float* t_feat = (const float*)d_in[2];
  const float* pref_v = (const float*)d_in[3];
  const float* pref_t = (const float*)d_in[4];
  const float* W_v = (const float*)d_in[5];
  const float* b_v = (const float*)d_in[6];
  const float* W_t = (const float*)d_in[7];
  const float* b_t = (const float*)d_in[8];
  const float* id_emb = (const float*)d_in[9];
  const float* conf = (const float*)d_in[10];
  float* out = (float*)d_out;

  float* ws = (float*)d_ws;
  float* xv = ws + O_XV;
  float* xt = ws + O_XT;
  float* x0 = ws + O_X0;
  float* eV = ws + O_EV;
  float* eT = ws + O_ET;
  float* wE = ws + O_WE;
  float* SV = ws + O_SV;
  float* ST = ws + O_STT;
  int* deg = (int*)(ws + O_DEG);
  int* row_ptr = (int*)(ws + O_RP);
  int* fill = (int*)(ws + O_FILL);
  int* srcs = (int*)(ws + O_SRC);
  int* bsum = (int*)(ws + O_BSUM);
  int* boff = (int*)(ws + O_BOFF);
  float* h1 = ws + O_H1;  // aliases xv (dead after gat_final)
  short* wsp = (short*)(ws + O_X0);  // split-W storage, dead before l2norm_all writes x0
  short* WvHi = wsp + SW_VHI;
  short* WvLo = wsp + SW_VLO;
  short* WtHi = wsp + SW_THI;
  short* WtLo = wsp + SW_TLO;

  const int NB = (NNODE + 255) / 256;  // 352

  // CSR build
  hipMemsetAsync(deg, 0, NNODE * sizeof(int), stream);
  deg_count_kernel<<<(NE + 255) / 256, 256, 0, stream>>>(ei, deg);
  block_sum_kernel<<<NB, 256, 0, stream>>>(deg, bsum);
  scan_bsum_kernel<<<1, 512, 0, stream>>>(bsum, boff, NB);
  scan_final_kernel<<<NB, 256, 0, stream>>>(deg, boff, row_ptr, fill);
  csr_fill_kernel<<<(NE + 255) / 256, 256, 0, stream>>>(ei, fill, srcs);

  // W split + swizzle (into X0 region; consumed by GEMMs before l2norm_all overwrites)
  wsplit_kernel<<<(2048 * 64 + 255) / 256, 256, 0, stream>>>(W_v, WvHi, WvLo, 2048 * 64);
  wsplit_kernel<<<(384 * 64 + 255) / 256, 256, 0, stream>>>(W_t, WtHi, WtLo, 384 * 64);

  // features = l2norm(leaky(feat @ W + b)) fused, into x[50000:]
  gemm_mfma_kernel<<<NITEM / 64, 256, 0, stream>>>(v_feat, WvHi, WvLo, b_v,
                                                   xv + (size_t)NUSER * 64, 2048);
  gemm_mfma_kernel<<<NITEM / 64, 256, 0, stream>>>(t_feat, WtHi, WtLo, b_t,
                                                   xt + (size_t)NUSER * 64, 384);

  // prefs + id l2norm (writes x0 -> split-W storage now dead)
  l2norm_all_kernel<<<(2 * NUSER + NNODE) / 16, 256, 0, stream>>>(pref_v, pref_t, id_emb,
                                                                  xv, xt, x0);

  // routing: 3 iterations, v+t fused per launch
  for (int it = 0; it < 3; ++it)
    routing_kernel<<<2 * NUSER / 4, 256, 0, stream>>>(xv, xt, row_ptr, srcs);

  // final GAT (both modalities) -> out[:,64:192], stash e & S
  gat_final_kernel<<<2 * NNODE / 4, 256, 0, stream>>>(xv, xt, row_ptr, srcs, eV, eT, SV, ST, out);

  // egcn
  egcn_h1_kernel<<<NNODE / 4, 256, 0, stream>>>(x0, row_ptr, srcs, eV, eT, SV, ST, conf, wE, h1);
  egcn_h2_kernel<<<NNODE / 4, 256, 0, stream>>>(x0, h1, row_ptr, srcs, wE, out);
}

// Round 3
// 973.049 us; speedup vs baseline: 1.7074x; 1.0877x over previous
//
#include <hip/hip_runtime.h>
#include <hip/hip_bf16.h>
#include <cstdint>
#include <cstddef>

#define NUSER 50000
#define NITEM 40000
#define NNODE 90000
#define NE    1000000
#define DIM   64
#define CAP   32   // LDS-cached neighbor rows per user wave (Poisson(10) degree; global fallback past CAP)

typedef __attribute__((ext_vector_type(8))) short short8;
typedef __attribute__((ext_vector_type(4))) float f32x4;

// ---------------- workspace layout (float element offsets) ----------------
constexpr size_t O_XVT  = 0;           // ushort[90000*128]  (5.76M floats)
constexpr size_t O_X0   = 5760000;     // float [90000*64]
constexpr size_t O_X0B  = 11520000;    // ushort[90000*64]   (2.88M floats)
constexpr size_t O_H1B  = 14400000;    // ushort[90000*64]
constexpr size_t O_XVF  = 17280000;    // float [40000*64] item v-features fp32
constexpr size_t O_XTF  = 19840000;    // float [40000*64]
constexpr size_t O_AE   = 22400000;    // float [1M]  e_v*conf0[src] per CSR slot
constexpr size_t O_BE   = 23400000;    // float [1M]  e_t*conf1[src]
constexpr size_t O_WE   = 24400000;    // float [1M]  egcn edge weight
constexpr size_t O_SV   = 25400000;    // float [90000] softmax denom v
constexpr size_t O_ST   = 25490000;    // float [90000]
constexpr size_t O_DEG  = 25580000;    // int [90000]
constexpr size_t O_RP   = 25670000;    // int [90001]
constexpr size_t O_FILL = 25770000;    // int [90000]
constexpr size_t O_SRC  = 25870000;    // int [1M]
constexpr size_t O_BSUM = 26870000;    // int [512]
constexpr size_t O_BOFF = 26871000;    // int [512]
constexpr size_t O_WSPL = 26880000;    // shorts: split-W storage (~312k shorts)
// split-W offsets within O_WSPL, in shorts:
constexpr size_t SW_VHI = 0;
constexpr size_t SW_VLO = 131072;
constexpr size_t SW_THI = 262144;
constexpr size_t SW_TLO = 286720;

__device__ __forceinline__ float leaky(float x) { return x >= 0.f ? x : 0.01f * x; }

__device__ __forceinline__ unsigned short f2bfu(float x) {
  __hip_bfloat16 h = __float2bfloat16(x);
  return *reinterpret_cast<unsigned short*>(&h);
}
__device__ __forceinline__ short f2bf(float x) { return (short)f2bfu(x); }
__device__ __forceinline__ float bf2f(short s) {
  unsigned int u = ((unsigned int)(unsigned short)s) << 16;
  return __uint_as_float(u);
}
// 8 bf16 (16B) -> 8 f32
__device__ __forceinline__ void bf8_to_f32(uint4 u, float* f) {
  f[0] = __uint_as_float(u.x << 16); f[1] = __uint_as_float(u.x & 0xffff0000u);
  f[2] = __uint_as_float(u.y << 16); f[3] = __uint_as_float(u.y & 0xffff0000u);
  f[4] = __uint_as_float(u.z << 16); f[5] = __uint_as_float(u.z & 0xffff0000u);
  f[6] = __uint_as_float(u.w << 16); f[7] = __uint_as_float(u.w & 0xffff0000u);
}
__device__ __forceinline__ uint4 f32_to_bf8(const float* f) {
  uint4 u;
  u.x = (uint32_t)f2bfu(f[0]) | ((uint32_t)f2bfu(f[1]) << 16);
  u.y = (uint32_t)f2bfu(f[2]) | ((uint32_t)f2bfu(f[3]) << 16);
  u.z = (uint32_t)f2bfu(f[4]) | ((uint32_t)f2bfu(f[5]) << 16);
  u.w = (uint32_t)f2bfu(f[6]) | ((uint32_t)f2bfu(f[7]) << 16);
  return u;
}
__device__ __forceinline__ void bf4_to_f32(uint2 u, float* f) {
  f[0] = __uint_as_float(u.x << 16); f[1] = __uint_as_float(u.x & 0xffff0000u);
  f[2] = __uint_as_float(u.y << 16); f[3] = __uint_as_float(u.y & 0xffff0000u);
}
__device__ __forceinline__ uint2 f32_to_bf4(const float* f) {
  uint2 u;
  u.x = (uint32_t)f2bfu(f[0]) | ((uint32_t)f2bfu(f[1]) << 16);
  u.y = (uint32_t)f2bfu(f[2]) | ((uint32_t)f2bfu(f[3]) << 16);
  return u;
}

// ---------------- CSR construction ----------------
__global__ void deg_count_kernel(const int* __restrict__ ei, int* __restrict__ deg) {
  int e = blockIdx.x * 256 + threadIdx.x;
  if (e >= NE) return;
  atomicAdd(&deg[ei[NE + e]], 1);
}

__global__ void block_sum_kernel(const int* __restrict__ deg, int* __restrict__ bsum) {
  __shared__ int sd[4];
  int i = blockIdx.x * 256 + threadIdx.x;
  int v = (i < NNODE) ? deg[i] : 0;
#pragma unroll
  for (int off = 32; off > 0; off >>= 1) v += __shfl_xor(v, off, 64);
  if ((threadIdx.x & 63) == 0) sd[threadIdx.x >> 6] = v;
  __syncthreads();
  if (threadIdx.x == 0) bsum[blockIdx.x] = sd[0] + sd[1] + sd[2] + sd[3];
}

__global__ void scan_bsum_kernel(const int* __restrict__ bsum, int* __restrict__ boff, int nb) {
  __shared__ int s[512];
  int t = threadIdx.x;
  int v = (t < nb) ? bsum[t] : 0;
  s[t] = v;
  __syncthreads();
  for (int off = 1; off < 512; off <<= 1) {
    int x = (t >= off) ? s[t - off] : 0;
    __syncthreads();
    s[t] += x;
    __syncthreads();
  }
  if (t < nb) boff[t] = s[t] - v;
}

__global__ void scan_final_kernel(const int* __restrict__ deg, const int* __restrict__ boff,
                                  int* __restrict__ row_ptr, int* __restrict__ fill) {
  __shared__ int s[256];
  int t = threadIdx.x;
  int i = blockIdx.x * 256 + t;
  int v = (i < NNODE) ? deg[i] : 0;
  s[t] = v;
  __syncthreads();
  for (int off = 1; off < 256; off <<= 1) {
    int x = (t >= off) ? s[t - off] : 0;
    __syncthreads();
    s[t] += x;
    __syncthreads();
  }
  int incl = s[t];
  int base = boff[blockIdx.x];
  if (i < NNODE) {
    row_ptr[i] = base + incl - v;
    fill[i] = base + incl - v;
    if (i == NNODE - 1) row_ptr[NNODE] = base + incl;
  }
}

__global__ void csr_fill_kernel(const int* __restrict__ ei, int* __restrict__ fill,
                                int* __restrict__ srcs) {
  int e = blockIdx.x * 256 + threadIdx.x;
  if (e >= NE) return;
  int s = ei[e], d = ei[NE + e];
  int slot = atomicAdd(&fill[d], 1);
  srcs[slot] = s;
}

// ---------------- W split: fp32 -> bf16 hi/lo, MFMA-fragment-linear --------
__global__ void wsplit_kernel(const float* __restrict__ W, short* __restrict__ hi,
                              short* __restrict__ lo, int nelem) {
  int t = blockIdx.x * 256 + threadIdx.x;
  if (t >= nelem) return;
  int j = t & 7, sl = (t >> 3) & 15, q = (t >> 7) & 3, nt = (t >> 9) & 3, kt = t >> 11;
  int k = kt * 32 + q * 8 + j, n = nt * 16 + sl;
  float x = W[k * 64 + n];
  short h = f2bf(x);
  hi[t] = h;
  lo[t] = f2bf(x - bf2f(h));
}

// ---------------- GEMM: fp32 XF + bf16 XVT rows = l2norm(leaky(A@W+b)) -----
__global__ __launch_bounds__(256) void gemm_mfma_kernel(const float* __restrict__ A,
                                                        const short* __restrict__ Whi,
                                                        const short* __restrict__ Wlo,
                                                        const float* __restrict__ bias,
                                                        float* __restrict__ outF,
                                                        unsigned short* __restrict__ xvt,
                                                        int colbase, int K) {
  __shared__ short Bsh[8192];
  __shared__ short Bsl[8192];
  int tid = threadIdx.x;
  int w = tid >> 6, lane = tid & 63, q = lane >> 4, sl = lane & 15;
  int m0 = blockIdx.x * 64;
  const float* arow = A + (size_t)(m0 + w * 16 + sl) * K;
  f32x4 acc[4] = {{0.f, 0.f, 0.f, 0.f}, {0.f, 0.f, 0.f, 0.f},
                  {0.f, 0.f, 0.f, 0.f}, {0.f, 0.f, 0.f, 0.f}};
  int nchunk = K >> 7;
  for (int c = 0; c < nchunk; ++c) {
    __syncthreads();
    const float4* srch = (const float4*)(Whi + (size_t)c * 8192);
    const float4* srcl = (const float4*)(Wlo + (size_t)c * 8192);
    float4* dsth = (float4*)Bsh;
    float4* dstl = (float4*)Bsl;
#pragma unroll
    for (int r = 0; r < 4; ++r) {
      dsth[r * 256 + tid] = srch[r * 256 + tid];
      dstl[r * 256 + tid] = srcl[r * 256 + tid];
    }
    __syncthreads();
#pragma unroll
    for (int kt = 0; kt < 4; ++kt) {
      int k = c * 128 + kt * 32 + q * 8;
      float4 a0 = *(const float4*)&arow[k];
      float4 a1 = *(const float4*)&arow[k + 4];
      float av[8] = {a0.x, a0.y, a0.z, a0.w, a1.x, a1.y, a1.z, a1.w};
      short8 ah, al;
#pragma unroll
      for (int j = 0; j < 8; ++j) {
        short h = f2bf(av[j]);
        ah[j] = h;
        al[j] = f2bf(av[j] - bf2f(h));
      }
#pragma unroll
      for (int nt = 0; nt < 4; ++nt) {
        short8 bh = *(short8*)&Bsh[(kt * 4 + nt) * 512 + lane * 8];
        short8 bl = *(short8*)&Bsl[(kt * 4 + nt) * 512 + lane * 8];
        acc[nt] = __builtin_amdgcn_mfma_f32_16x16x32_bf16(ah, bh, acc[nt], 0, 0, 0);
        acc[nt] = __builtin_amdgcn_mfma_f32_16x16x32_bf16(ah, bl, acc[nt], 0, 0, 0);
        acc[nt] = __builtin_amdgcn_mfma_f32_16x16x32_bf16(al, bh, acc[nt], 0, 0, 0);
      }
    }
  }
  float bnt[4];
#pragma unroll
  for (int nt = 0; nt < 4; ++nt) bnt[nt] = bias[nt * 16 + sl];
  float v[4][4];
#pragma unroll
  for (int nt = 0; nt < 4; ++nt)
#pragma unroll
    for (int i = 0; i < 4; ++i) v[nt][i] = leaky(acc[nt][i] + bnt[nt]);
#pragma unroll
  for (int i = 0; i < 4; ++i) {
    float ss = v[0][i] * v[0][i] + v[1][i] * v[1][i] + v[2][i] * v[2][i] + v[3][i] * v[3][i];
    ss += __shfl_xor(ss, 1);
    ss += __shfl_xor(ss, 2);
    ss += __shfl_xor(ss, 4);
    ss += __shfl_xor(ss, 8);
    float rinv = 1.f / fmaxf(sqrtf(ss), 1e-12f);
    int row = m0 + w * 16 + q * 4 + i;
#pragma unroll
    for (int nt = 0; nt < 4; ++nt) {
      float val = v[nt][i] * rinv;
      outF[(size_t)row * 64 + nt * 16 + sl] = val;
      xvt[(size_t)(NUSER + row) * 128 + colbase + nt * 16 + sl] = f2bfu(val);
    }
  }
}

// ---------------- id l2norm -> x0 fp32 + bf16 ----------------
__global__ __launch_bounds__(256) void l2norm_id_kernel(const float* __restrict__ id,
                                                        float* __restrict__ x0,
                                                        unsigned short* __restrict__ X0b) {
  int wid = (blockIdx.x * 256 + threadIdx.x) >> 6;
  int lane = threadIdx.x & 63, sub = lane >> 4, sl = lane & 15;
  int r = wid * 4 + sub;
  if (r >= NNODE) return;
  float4 v = *(const float4*)&id[(size_t)r * 64 + sl * 4];
  float ss = v.x * v.x + v.y * v.y + v.z * v.z + v.w * v.w;
  ss += __shfl_xor(ss, 1);
  ss += __shfl_xor(ss, 2);
  ss += __shfl_xor(ss, 4);
  ss += __shfl_xor(ss, 8);
  float rinv = 1.f / fmaxf(sqrtf(ss), 1e-12f);
  float f[4] = {v.x * rinv, v.y * rinv, v.z * rinv, v.w * rinv};
  *(float4*)&x0[(size_t)r * 64 + sl * 4] = *(float4*)f;
  *(uint2*)&X0b[(size_t)r * 64 + sl * 4] = f32_to_bf4(f);
}

// ---------------- fused: 3 routing iters + user-side final GAT -------------
// wave per user; 16-lane subgroup per edge; lane holds 8 elems of (v|t) half.
__global__ __launch_bounds__(256) void routing_user_kernel(
    const float* __restrict__ pref_v, const float* __restrict__ pref_t,
    unsigned short* __restrict__ XVT,
    const int* __restrict__ rp, const int* __restrict__ srcs,
    const float* __restrict__ conf,
    float* __restrict__ Ae, float* __restrict__ Be,
    float* __restrict__ SV, float* __restrict__ ST,
    float* __restrict__ out) {
  __shared__ unsigned short cache[4][CAP * 128];  // 32 KB/block
  int wv = threadIdx.x >> 6;
  int u = blockIdx.x * 4 + wv;
  if (u >= NUSER) return;
  int lane = threadIdx.x & 63;
  int sub = lane >> 4, sl = lane & 15, half = sl >> 3, e8 = sl & 7;
  unsigned short* myc = cache[wv];

  const float* psrc = half ? pref_t : pref_v;
  float p[8];
  *(float4*)&p[0] = *(const float4*)&psrc[(size_t)u * 64 + e8 * 8];
  *(float4*)&p[4] = *(const float4*)&psrc[(size_t)u * 64 + e8 * 8 + 4];
  float ss = 0.f;
#pragma unroll
  for (int k = 0; k < 8; ++k) ss += p[k] * p[k];
  ss += __shfl_xor(ss, 1); ss += __shfl_xor(ss, 2); ss += __shfl_xor(ss, 4);
  float rinv = 1.f / fmaxf(sqrtf(ss), 1e-12f);
#pragma unroll
  for (int k = 0; k < 8; ++k) p[k] *= rinv;

  int jb = rp[u], je = rp[u + 1], deg = je - jb;

  for (int it = 0; it < 3; ++it) {
    float S = 0.f;
    float acc[8] = {0.f, 0.f, 0.f, 0.f, 0.f, 0.f, 0.f, 0.f};
    for (int i0 = 0; i0 < deg; i0 += 4) {
      int i = i0 + sub;
      bool valid = i < deg;
      int ii = valid ? i : 0;
      int j = jb + ii;
      int s = srcs[j];
      uint4 u4;
      if (it == 0) {
        u4 = *(const uint4*)&XVT[(size_t)s * 128 + sl * 8];
        if (valid && i < CAP) *(uint4*)&myc[i * 128 + sl * 8] = u4;
      } else {
        if (ii < CAP) u4 = *(const uint4*)&myc[ii * 128 + sl * 8];
        else u4 = *(const uint4*)&XVT[(size_t)s * 128 + sl * 8];
      }
      float f[8];
      bf8_to_f32(u4, f);
      float d = 0.f;
#pragma unroll
      for (int k = 0; k < 8; ++k) d += p[k] * f[k];
      d += __shfl_xor(d, 1); d += __shfl_xor(d, 2); d += __shfl_xor(d, 4);
      float e = valid ? __expf(d) : 0.f;
      S += e;
#pragma unroll
      for (int k = 0; k < 8; ++k) acc[k] += e * f[k];
    }
    S += __shfl_xor(S, 16); S += __shfl_xor(S, 32);
#pragma unroll
    for (int k = 0; k < 8; ++k) {
      acc[k] += __shfl_xor(acc[k], 16);
      acc[k] += __shfl_xor(acc[k], 32);
    }
    if (deg > 0) {
      float r = 1.f / S;
#pragma unroll
      for (int k = 0; k < 8; ++k) p[k] += acc[k] * r;
    }
    ss = 0.f;
#pragma unroll
    for (int k = 0; k < 8; ++k) ss += p[k] * p[k];
    ss += __shfl_xor(ss, 1); ss += __shfl_xor(ss, 2); ss += __shfl_xor(ss, 4);
    rinv = 1.f / fmaxf(sqrtf(ss), 1e-12f);
#pragma unroll
    for (int k = 0; k < 8; ++k) p[k] *= rinv;
  }

  // user-side final GAT with final pref
  float S = 0.f;
  float acc[8] = {0.f, 0.f, 0.f, 0.f, 0.f, 0.f, 0.f, 0.f};
  for (int i0 = 0; i0 < deg; i0 += 4) {
    int i = i0 + sub;
    bool valid = i < deg;
    int ii = valid ? i : 0;
    int j = jb + ii;
    int s = srcs[j];
    uint4 u4;
    if (ii < CAP) u4 = *(const uint4*)&myc[ii * 128 + sl * 8];
    else u4 = *(const uint4*)&XVT[(size_t)s * 128 + sl * 8];
    float f[8];
    bf8_to_f32(u4, f);
    float d = 0.f;
#pragma unroll
    for (int k = 0; k < 8; ++k) d += p[k] * f[k];
    d += __shfl_xor(d, 1); d += __shfl_xor(d, 2); d += __shfl_xor(d, 4);
    float dot_o = __shfl_xor(d, 8);
    float e = valid ? __expf(d) : 0.f;
    S += e;
#pragma unroll
    for (int k = 0; k < 8; ++k) acc[k] += e * f[k];
    if (valid && sl == 0) {
      float2 c = *(const float2*)&conf[2 * s];
      Ae[j] = e * c.x;               // lane 0 is v-half: e = e_v
      Be[j] = __expf(dot_o) * c.y;   // e_t
    }
  }
  S += __shfl_xor(S, 16); S += __shfl_xor(S, 32);
#pragma unroll
  for (int k = 0; k < 8; ++k) {
    acc[k] += __shfl_xor(acc[k], 16);
    acc[k] += __shfl_xor(acc[k], 32);
  }
  float St = __shfl(S, 8);
  if (lane == 0) { SV[u] = S; ST[u] = St; }
  if (sub == 0) {
    float o[8];
    if (deg > 0) {
      float r = 1.f / S;
#pragma unroll
      for (int k = 0; k < 8; ++k) o[k] = p[k] + leaky(acc[k] * r);
    } else {
#pragma unroll
      for (int k = 0; k < 8; ++k) o[k] = p[k];
    }
    size_t ob = (size_t)u * 192 + 64 + half * 64 + e8 * 8;
    *(float4*)&out[ob] = *(float4*)&o[0];
    *(float4*)&out[ob + 4] = *(float4*)&o[4];
    *(uint4*)&XVT[(size_t)u * 128 + sl * 8] = f32_to_bf8(p);
  }
}

// ---------------- item-side final GAT ----------------
__global__ __launch_bounds__(256) void gat_item_kernel(
    const unsigned short* __restrict__ XVT,
    const float* __restrict__ XVf, const float* __restrict__ XTf,
    const int* __restrict__ rp, const int* __restrict__ srcs,
    const float* __restrict__ conf,
    float* __restrict__ Ae, float* __restrict__ Be,
    float* __restrict__ SV, float* __restrict__ ST,
    float* __restrict__ out) {
  int wid = (blockIdx.x * 256 + threadIdx.x) >> 6;
  if (wid >= NITEM) return;
  int lane = threadIdx.x & 63;
  int sub = lane >> 4, sl = lane & 15, half = sl >> 3, e8 = sl & 7;
  int row = NUSER + wid;
  const float* xsrc = half ? XTf : XVf;
  float xn[8];
  *(float4*)&xn[0] = *(const float4*)&xsrc[(size_t)wid * 64 + e8 * 8];
  *(float4*)&xn[4] = *(const float4*)&xsrc[(size_t)wid * 64 + e8 * 8 + 4];
  int jb = rp[row], je = rp[row + 1], deg = je - jb;
  float S = 0.f;
  float acc[8] = {0.f, 0.f, 0.f, 0.f, 0.f, 0.f, 0.f, 0.f};
  for (int i0 = 0; i0 < deg; i0 += 4) {
    int i = i0 + sub;
    bool valid = i < deg;
    int j = jb + (valid ? i : 0);
    int s = srcs[j];
    uint4 u4 = *(const uint4*)&XVT[(size_t)s * 128 + sl * 8];
    float f[8];
    bf8_to_f32(u4, f);
    float d = 0.f;
#pragma unroll
    for (int k = 0; k < 8; ++k) d += xn[k] * f[k];
    d += __shfl_xor(d, 1); d += __shfl_xor(d, 2); d += __shfl_xor(d, 4);
    float dot_o = __shfl_xor(d, 8);
    float e = valid ? __expf(d) : 0.f;
    S += e;
#pragma unroll
    for (int k = 0; k < 8; ++k) acc[k] += e * f[k];
    if (valid && sl == 0) {
      float2 c = *(const float2*)&conf[2 * s];
      Ae[j] = e * c.x;
      Be[j] = __expf(dot_o) * c.y;
    }
  }
  S += __shfl_xor(S, 16); S += __shfl_xor(S, 32);
#pragma unroll
  for (int k = 0; k < 8; ++k) {
    acc[k] += __shfl_xor(acc[k], 16);
    acc[k] += __shfl_xor(acc[k], 32);
  }
  float St = __shfl(S, 8);
  if (lane == 0) { SV[row] = S; ST[row] = St; }
  if (sub == 0) {
    float o[8];
    if (deg > 0) {
      float r = 1.f / S;
#pragma unroll
      for (int k = 0; k < 8; ++k) o[k] = xn[k] + leaky(acc[k] * r);
    } else {
#pragma unroll
      for (int k = 0; k < 8; ++k) o[k] = xn[k];
    }
    size_t ob = (size_t)row * 192 + 64 + half * 64 + e8 * 8;
    *(float4*)&out[ob] = *(float4*)&o[0];
    *(float4*)&out[ob + 4] = *(float4*)&o[4];
  }
}

// ---------------- egcn hop 1: wE + weighted mean of x0 (bf16 gathers) ------
__global__ __launch_bounds__(256) void egcn_h1_kernel(
    const unsigned short* __restrict__ X0b,
    const int* __restrict__ rp, const int* __restrict__ srcs,
    const float* __restrict__ Ae, const float* __restrict__ Be,
    const float* __restrict__ SV, const float* __restrict__ ST,
    float* __restrict__ wE, unsigned short* __restrict__ H1b) {
  int wid = (blockIdx.x * 256 + threadIdx.x) >> 6;
  if (wid >= NNODE) return;
  int lane = threadIdx.x & 63, sub = lane >> 4, sl = lane & 15;
  int jb = rp[wid], je = rp[wid + 1], deg = je - jb;
  float rv = 0.f, rt = 0.f;
  if (deg > 0) { rv = 0.5f / SV[wid]; rt = 0.5f / ST[wid]; }
  float acc[4] = {0.f, 0.f, 0.f, 0.f};
  for (int i0 = 0; i0 < deg; i0 += 4) {
    int i = i0 + sub;
    bool valid = i < deg;
    int j = jb + (valid ? i : 0);
    int s = srcs[j];
    float w = fmaxf(fmaxf(rv * Ae[j], rt * Be[j]), 0.f);
    if (!valid) w = 0.f;
    if (valid && sl == 0) wE[j] = w;
    uint2 u2 = *(const uint2*)&X0b[(size_t)s * 64 + sl * 4];
    float f[4];
    bf4_to_f32(u2, f);
#pragma unroll
    for (int k = 0; k < 4; ++k) acc[k] += w * f[k];
  }
#pragma unroll
  for (int k = 0; k < 4; ++k) {
    acc[k] += __shfl_xor(acc[k], 16);
    acc[k] += __shfl_xor(acc[k], 32);
  }
  if (sub == 0) {
    float h[4] = {0.f, 0.f, 0.f, 0.f};
    if (deg > 0) {
      float r = 1.f / (float)deg;
#pragma unroll
      for (int k = 0; k < 4; ++k) h[k] = leaky(acc[k] * r);
    }
    *(uint2*)&H1b[(size_t)wid * 64 + sl * 4] = f32_to_bf4(h);
  }
}

// ---------------- egcn hop 2 + id_rep write ----------------
__global__ __launch_bounds__(256) void egcn_h2_kernel(
    const float* __restrict__ x0, const unsigned short* __restrict__ H1b,
    const int* __restrict__ rp, const int* __restrict__ srcs,
    const float* __restrict__ wE, float* __restrict__ out) {
  int wid = (blockIdx.x * 256 + threadIdx.x) >> 6;
  if (wid >= NNODE) return;
  int lane = threadIdx.x & 63, sub = lane >> 4, sl = lane & 15;
  int jb = rp[wid], je = rp[wid + 1], deg = je - jb;
  float acc[4] = {0.f, 0.f, 0.f, 0.f};
  for (int i0 = 0; i0 < deg; i0 += 4) {
    int i = i0 + sub;
    bool valid = i < deg;
    int j = jb + (valid ? i : 0);
    int s = srcs[j];
    float w = valid ? wE[j] : 0.f;
    uint2 u2 = *(const uint2*)&H1b[(size_t)s * 64 + sl * 4];
    float f[4];
    bf4_to_f32(u2, f);
#pragma unroll
    for (int k = 0; k < 4; ++k) acc[k] += w * f[k];
  }
#pragma unroll
  for (int k = 0; k < 4; ++k) {
    acc[k] += __shfl_xor(acc[k], 16);
    acc[k] += __shfl_xor(acc[k], 32);
  }
  if (sub == 0) {
    float h2[4] = {0.f, 0.f, 0.f, 0.f};
    if (deg > 0) {
      float r = 1.f / (float)deg;
#pragma unroll
      for (int k = 0; k < 4; ++k) h2[k] = leaky(acc[k] * r);
    }
    float4 a = *(const float4*)&x0[(size_t)wid * 64 + sl * 4];
    uint2 u2 = *(const uint2*)&H1b[(size_t)wid * 64 + sl * 4];
    float h1[4];
    bf4_to_f32(u2, h1);
    float4 o = {a.x + h1[0] + h2[0], a.y + h1[1] + h2[1],
                a.z + h1[2] + h2[2], a.w + h1[3] + h2[3]};
    *(float4*)&out[(size_t)wid * 192 + sl * 4] = o;
  }
}

// ---------------- launcher ----------------
extern "C" void kernel_launch(void* const* d_in, const int* in_sizes, int n_in,
                              void* d_out, int out_size, void* d_ws, size_t ws_size,
                              hipStream_t stream) {
  const int* ei = (const int*)d_in[0];
  const float* v_feat = (const float*)d_in[1];
  const float* t_feat = (const float*)d_in[2];
  const float* pref_v = (const float*)d_in[3];
  const float* pref_t = (const float*)d_in[4];
  const float* W_v = (const float*)d_in[5];
  const float* b_v = (const float*)d_in[6];
  const float* W_t = (const float*)d_in[7];
  const float* b_t = (const float*)d_in[8];
  const float* id_emb = (const float*)d_in[9];
  const float* conf = (const float*)d_in[10];
  float* out = (float*)d_out;

  float* ws = (float*)d_ws;
  unsigned short* XVT = (unsigned short*)(ws + O_XVT);
  float* x0 = ws + O_X0;
  unsigned short* X0b = (unsigned short*)(ws + O_X0B);
  unsigned short* H1b = (unsigned short*)(ws + O_H1B);
  float* XVf = ws + O_XVF;
  float* XTf = ws + O_XTF;
  float* Ae = ws + O_AE;
  float* Be = ws + O_BE;
  float* wE = ws + O_WE;
  float* SV = ws + O_SV;
  float* ST = ws + O_ST;
  int* deg = (int*)(ws + O_DEG);
  int* row_ptr = (int*)(ws + O_RP);
  int* fill = (int*)(ws + O_FILL);
  int* srcs = (int*)(ws + O_SRC);
  int* bsum = (int*)(ws + O_BSUM);
  int* boff = (int*)(ws + O_BOFF);
  short* wsp = (short*)(ws + O_WSPL);
  short* WvHi = wsp + SW_VHI;
  short* WvLo = wsp + SW_VLO;
  short* WtHi = wsp + SW_THI;
  short* WtLo = wsp + SW_TLO;

  const int NB = (NNODE + 255) / 256;  // 352

  // CSR build
  hipMemsetAsync(deg, 0, NNODE * sizeof(int), stream);
  deg_count_kernel<<<(NE + 255) / 256, 256, 0, stream>>>(ei, deg);
  block_sum_kernel<<<NB, 256, 0, stream>>>(deg, bsum);
  scan_bsum_kernel<<<1, 512, 0, stream>>>(bsum, boff, NB);
  scan_final_kernel<<<NB, 256, 0, stream>>>(deg, boff, row_ptr, fill);
  csr_fill_kernel<<<(NE + 255) / 256, 256, 0, stream>>>(ei, fill, srcs);

  // W split
  wsplit_kernel<<<(2048 * 64 + 255) / 256, 256, 0, stream>>>(W_v, WvHi, WvLo, 2048 * 64);
  wsplit_kernel<<<(384 * 64 + 255) / 256, 256, 0, stream>>>(W_t, WtHi, WtLo, 384 * 64);

  // item features: fp32 arrays + bf16 XVT item rows
  gemm_mfma_kernel<<<NITEM / 64, 256, 0, stream>>>(v_feat, WvHi, WvLo, b_v, XVf, XVT, 0, 2048);
  gemm_mfma_kernel<<<NITEM / 64, 256, 0, stream>>>(t_feat, WtHi, WtLo, b_t, XTf, XVT, 64, 384);

  // id l2norm
  l2norm_id_kernel<<<NNODE / 16, 256, 0, stream>>>(id_emb, x0, X0b);

  // fused routing (3 iters) + user-side GAT; writes XVT user rows, Ae/Be/SV/ST, out cols 64..191
  routing_user_kernel<<<NUSER / 4, 256, 0, stream>>>(pref_v, pref_t, XVT, row_ptr, srcs, conf,
                                                     Ae, Be, SV, ST, out);

  // item-side GAT
  gat_item_kernel<<<NITEM / 4, 256, 0, stream>>>(XVT, XVf, XTf, row_ptr, srcs, conf,
                                                 Ae, Be, SV, ST, out);

  // egcn
  egcn_h1_kernel<<<NNODE / 4, 256, 0, stream>>>(X0b, row_ptr, srcs, Ae, Be, SV, ST, wE, H1b);
  egcn_h2_kernel<<<NNODE / 4, 256, 0, stream>>>(x0, H1b, row_ptr, srcs, wE, out);
}

// Round 4
// 893.584 us; speedup vs baseline: 1.8592x; 1.0889x over previous
//
#include <hip/hip_runtime.h>
#include <hip/hip_bf16.h>
#include <cstdint>
#include <cstddef>

#define NUSER 50000
#define NITEM 40000
#define NNODE 90000
#define NE    1000000
#define DIM   64
#define CAP   32    // LDS-cached neighbor rows per user wave
#define ESTN  128   // per-wave e-stash capacity (edges)

typedef __attribute__((ext_vector_type(8))) short short8;
typedef __attribute__((ext_vector_type(4))) float f32x4;

// ---------------- workspace layout (float element offsets) ----------------
constexpr size_t O_XVT  = 0;           // ushort[90000*128]
constexpr size_t O_X0   = 5760000;     // float [90000*64]
constexpr size_t O_X0B  = 11520000;    // ushort[90000*64]
constexpr size_t O_H1B  = 14400000;    // ushort[90000*64]
constexpr size_t O_XVF  = 17280000;    // float [40000*64]
constexpr size_t O_XTF  = 19840000;    // float [40000*64]
constexpr size_t O_AE   = 22400000;    // float [1M]
constexpr size_t O_BE   = 23400000;    // float [1M]
constexpr size_t O_WE   = 24400000;    // float [1M]
constexpr size_t O_SV   = 25400000;    // float [90000]
constexpr size_t O_ST   = 25490000;    // float [90000]
constexpr size_t O_DEG  = 25580000;    // int [90000]
constexpr size_t O_RP   = 25670000;    // int [90001]
constexpr size_t O_FILL = 25770000;    // int [90000]
constexpr size_t O_SRC  = 25870000;    // int [1M]
constexpr size_t O_BSUM = 26870000;    // int [512]
constexpr size_t O_WSPL = 26880000;    // shorts (~312k)
constexpr size_t O_PV   = 27040000;    // float [4*40000*64] gemm-v partials
constexpr size_t O_PT   = 37280000;    // float [40000*64]   gemm-t partial
// split-W offsets within O_WSPL, in shorts:
constexpr size_t SW_VHI = 0;
constexpr size_t SW_VLO = 131072;
constexpr size_t SW_THI = 262144;
constexpr size_t SW_TLO = 286720;

// mega_prep block classes
#define B_GV 2500   // gemm_v: 4 segs x 625
#define B_GT 625
#define B_DC 1024
#define B_LN 1024
#define BASE_GT 2500
#define BASE_DC 3125
#define BASE_LN 4149
#define MEGA_BLOCKS 5173

__device__ __forceinline__ float leaky(float x) { return x >= 0.f ? x : 0.01f * x; }

__device__ __forceinline__ unsigned short f2bfu(float x) {
  __hip_bfloat16 h = __float2bfloat16(x);
  return *reinterpret_cast<unsigned short*>(&h);
}
__device__ __forceinline__ short f2bf(float x) { return (short)f2bfu(x); }
__device__ __forceinline__ float bf2f(short s) {
  unsigned int u = ((unsigned int)(unsigned short)s) << 16;
  return __uint_as_float(u);
}
__device__ __forceinline__ void bf8_to_f32(uint4 u, float* f) {
  f[0] = __uint_as_float(u.x << 16); f[1] = __uint_as_float(u.x & 0xffff0000u);
  f[2] = __uint_as_float(u.y << 16); f[3] = __uint_as_float(u.y & 0xffff0000u);
  f[4] = __uint_as_float(u.z << 16); f[5] = __uint_as_float(u.z & 0xffff0000u);
  f[6] = __uint_as_float(u.w << 16); f[7] = __uint_as_float(u.w & 0xffff0000u);
}
__device__ __forceinline__ uint4 f32_to_bf8(const float* f) {
  uint4 u;
  u.x = (uint32_t)f2bfu(f[0]) | ((uint32_t)f2bfu(f[1]) << 16);
  u.y = (uint32_t)f2bfu(f[2]) | ((uint32_t)f2bfu(f[3]) << 16);
  u.z = (uint32_t)f2bfu(f[4]) | ((uint32_t)f2bfu(f[5]) << 16);
  u.w = (uint32_t)f2bfu(f[6]) | ((uint32_t)f2bfu(f[7]) << 16);
  return u;
}
__device__ __forceinline__ void bf4_to_f32(uint2 u, float* f) {
  f[0] = __uint_as_float(u.x << 16); f[1] = __uint_as_float(u.x & 0xffff0000u);
  f[2] = __uint_as_float(u.y << 16); f[3] = __uint_as_float(u.y & 0xffff0000u);
}
__device__ __forceinline__ uint2 f32_to_bf4(const float* f) {
  uint2 u;
  u.x = (uint32_t)f2bfu(f[0]) | ((uint32_t)f2bfu(f[1]) << 16);
  u.y = (uint32_t)f2bfu(f[2]) | ((uint32_t)f2bfu(f[3]) << 16);
  return u;
}

// ---------------- W split: fp32 -> bf16 hi/lo, MFMA-fragment-linear --------
__global__ __launch_bounds__(256) void wsplit_all_kernel(const float* __restrict__ Wv,
                                                         const float* __restrict__ Wt,
                                                         short* __restrict__ base) {
  int t = blockIdx.x * 256 + threadIdx.x;
  const int NV = 2048 * 64, NT = 384 * 64;
  const float* W;
  short *hi, *lo;
  int idx;
  if (t < NV) { W = Wv; hi = base + SW_VHI; lo = base + SW_VLO; idx = t; }
  else if (t < NV + NT) { W = Wt; hi = base + SW_THI; lo = base + SW_TLO; idx = t - NV; }
  else return;
  int j = idx & 7, sl = (idx >> 3) & 15, q = (idx >> 7) & 3, nt = (idx >> 9) & 3, kt = idx >> 11;
  int k = kt * 32 + q * 8 + j, n = nt * 16 + sl;
  float x = W[k * 64 + n];
  short h = f2bf(x);
  hi[idx] = h;
  lo[idx] = f2bf(x - bf2f(h));
}

// ---------------- GEMM partial (device fn, no epilogue) ----------------
__device__ __forceinline__ void gemm_partial(const float* __restrict__ A,
                                             const short* __restrict__ Whi,
                                             const short* __restrict__ Wlo,
                                             float* __restrict__ P, size_t prow0,
                                             short* Bsh, short* Bsl,
                                             int m0, int K, int kofs, int nchunk) {
  int tid = threadIdx.x;
  int w = tid >> 6, lane = tid & 63, q = lane >> 4, sl = lane & 15;
  const float* arow = A + (size_t)(m0 + w * 16 + sl) * K + kofs;
  f32x4 acc[4] = {{0.f, 0.f, 0.f, 0.f}, {0.f, 0.f, 0.f, 0.f},
                  {0.f, 0.f, 0.f, 0.f}, {0.f, 0.f, 0.f, 0.f}};
  for (int c = 0; c < nchunk; ++c) {
    __syncthreads();
    const float4* srch = (const float4*)(Whi + (size_t)c * 8192);
    const float4* srcl = (const float4*)(Wlo + (size_t)c * 8192);
    float4* dsth = (float4*)Bsh;
    float4* dstl = (float4*)Bsl;
#pragma unroll
    for (int r = 0; r < 4; ++r) {
      dsth[r * 256 + tid] = srch[r * 256 + tid];
      dstl[r * 256 + tid] = srcl[r * 256 + tid];
    }
    __syncthreads();
#pragma unroll
    for (int kt = 0; kt < 4; ++kt) {
      int k = c * 128 + kt * 32 + q * 8;
      float4 a0 = *(const float4*)&arow[k];
      float4 a1 = *(const float4*)&arow[k + 4];
      float av[8] = {a0.x, a0.y, a0.z, a0.w, a1.x, a1.y, a1.z, a1.w};
      short8 ah, al;
#pragma unroll
      for (int j = 0; j < 8; ++j) {
        short h = f2bf(av[j]);
        ah[j] = h;
        al[j] = f2bf(av[j] - bf2f(h));
      }
#pragma unroll
      for (int nt = 0; nt < 4; ++nt) {
        short8 bh = *(short8*)&Bsh[(kt * 4 + nt) * 512 + lane * 8];
        short8 bl = *(short8*)&Bsl[(kt * 4 + nt) * 512 + lane * 8];
        acc[nt] = __builtin_amdgcn_mfma_f32_16x16x32_bf16(ah, bh, acc[nt], 0, 0, 0);
        acc[nt] = __builtin_amdgcn_mfma_f32_16x16x32_bf16(ah, bl, acc[nt], 0, 0, 0);
        acc[nt] = __builtin_amdgcn_mfma_f32_16x16x32_bf16(al, bh, acc[nt], 0, 0, 0);
      }
    }
  }
#pragma unroll
  for (int i = 0; i < 4; ++i) {
    int row = m0 + w * 16 + q * 4 + i;
#pragma unroll
    for (int nt = 0; nt < 4; ++nt)
      P[(prow0 + row) * 64 + nt * 16 + sl] = acc[nt][i];
  }
}

// ---------------- mega_prep: gemm_v(4 segs) | gemm_t | deg_count | id l2norm ----
__global__ __launch_bounds__(256) void mega_prep_kernel(
    const float* __restrict__ v_feat, const float* __restrict__ t_feat,
    const short* __restrict__ wsp,
    const int* __restrict__ ei, int* __restrict__ deg,
    const float* __restrict__ id_emb, float* __restrict__ x0,
    unsigned short* __restrict__ X0b,
    float* __restrict__ Pv, float* __restrict__ Pt) {
  __shared__ short Bsh[8192];
  __shared__ short Bsl[8192];
  int b = blockIdx.x;
  if (b < B_GV) {
    int seg = b / 625, m0 = (b % 625) * 64;
    gemm_partial(v_feat, wsp + SW_VHI + (size_t)seg * 4 * 8192,
                 wsp + SW_VLO + (size_t)seg * 4 * 8192,
                 Pv, (size_t)seg * 40000, Bsh, Bsl, m0, 2048, seg * 512, 4);
  } else if (b < BASE_DC) {
    int m0 = (b - BASE_GT) * 64;
    gemm_partial(t_feat, wsp + SW_THI, wsp + SW_TLO, Pt, 0, Bsh, Bsl, m0, 384, 0, 3);
  } else if (b < BASE_LN) {
    for (int e = (b - BASE_DC) * 256 + threadIdx.x; e < NE; e += B_DC * 256)
      atomicAdd(&deg[ei[NE + e]], 1);
  } else {
    int sl = threadIdx.x & 15;
    int qg = (b - BASE_LN) * 16 + (threadIdx.x >> 4);
    for (int r = qg; r < NNODE; r += B_LN * 16) {
      float4 v = *(const float4*)&id_emb[(size_t)r * 64 + sl * 4];
      float ss = v.x * v.x + v.y * v.y + v.z * v.z + v.w * v.w;
      ss += __shfl_xor(ss, 1); ss += __shfl_xor(ss, 2);
      ss += __shfl_xor(ss, 4); ss += __shfl_xor(ss, 8);
      float rinv = 1.f / fmaxf(sqrtf(ss), 1e-12f);
      float f[4] = {v.x * rinv, v.y * rinv, v.z * rinv, v.w * rinv};
      *(float4*)&x0[(size_t)r * 64 + sl * 4] = *(float4*)f;
      *(uint2*)&X0b[(size_t)r * 64 + sl * 4] = f32_to_bf4(f);
    }
  }
}

// ---------------- CSR scan (2 kernels) ----------------
__global__ __launch_bounds__(256) void scan_a_kernel(const int* __restrict__ deg,
                                                     int* __restrict__ bsum) {
  __shared__ int sd[4];
  int i = blockIdx.x * 256 + threadIdx.x;
  int v = (i < NNODE) ? deg[i] : 0;
#pragma unroll
  for (int off = 32; off > 0; off >>= 1) v += __shfl_xor(v, off, 64);
  if ((threadIdx.x & 63) == 0) sd[threadIdx.x >> 6] = v;
  __syncthreads();
  if (threadIdx.x == 0) bsum[blockIdx.x] = sd[0] + sd[1] + sd[2] + sd[3];
}

__global__ __launch_bounds__(256) void scan_b_kernel(const int* __restrict__ deg,
                                                     const int* __restrict__ bsum,
                                                     int* __restrict__ row_ptr,
                                                     int* __restrict__ fill) {
  __shared__ int s[256];
  __shared__ int sbase[4];
  int t = threadIdx.x, b = blockIdx.x;
  int v = (t < b) ? bsum[t] : 0;
  if (t + 256 < b) v += bsum[t + 256];
#pragma unroll
  for (int off = 32; off > 0; off >>= 1) v += __shfl_xor(v, off, 64);
  if ((t & 63) == 0) sbase[t >> 6] = v;
  int i = b * 256 + t;
  int d = (i < NNODE) ? deg[i] : 0;
  s[t] = d;
  __syncthreads();
  int base = sbase[0] + sbase[1] + sbase[2] + sbase[3];
  for (int off = 1; off < 256; off <<= 1) {
    int x = (t >= off) ? s[t - off] : 0;
    __syncthreads();
    s[t] += x;
    __syncthreads();
  }
  if (i < NNODE) {
    int excl = base + s[t] - d;
    row_ptr[i] = excl;
    fill[i] = excl;
    if (i == NNODE - 1) row_ptr[NNODE] = base + s[t];
  }
}

// ---------------- fill_epi: csr_fill | gemm epilogue ----------------
#define FE_FILL 512
__global__ __launch_bounds__(256) void fill_epi_kernel(
    const int* __restrict__ ei, int* __restrict__ fill, int* __restrict__ srcs,
    const float* __restrict__ Pv, const float* __restrict__ Pt,
    const float* __restrict__ b_v, const float* __restrict__ b_t,
    float* __restrict__ XVf, float* __restrict__ XTf,
    unsigned short* __restrict__ XVT) {
  int b = blockIdx.x;
  if (b < FE_FILL) {
    for (int e = b * 256 + threadIdx.x; e < NE; e += FE_FILL * 256) {
      int s = ei[e], d = ei[NE + e];
      int slot = atomicAdd(&fill[d], 1);
      srcs[slot] = s;
    }
    return;
  }
  int sl = threadIdx.x & 15;
  int q = (b - FE_FILL) * 16 + (threadIdx.x >> 4);  // 0..79999
  if (q >= 80000) return;
  int mod = q >= 40000;
  int r = q - mod * 40000;
  float4 a;
  if (!mod) {
    a = *(const float4*)&Pv[(size_t)r * 64 + sl * 4];
#pragma unroll
    for (int seg = 1; seg < 4; ++seg) {
      float4 p = *(const float4*)&Pv[((size_t)seg * 40000 + r) * 64 + sl * 4];
      a.x += p.x; a.y += p.y; a.z += p.z; a.w += p.w;
    }
  } else {
    a = *(const float4*)&Pt[(size_t)r * 64 + sl * 4];
  }
  float4 bias = *(const float4*)&(mod ? b_t : b_v)[sl * 4];
  float f[4] = {leaky(a.x + bias.x), leaky(a.y + bias.y),
                leaky(a.z + bias.z), leaky(a.w + bias.w)};
  float ss = f[0] * f[0] + f[1] * f[1] + f[2] * f[2] + f[3] * f[3];
  ss += __shfl_xor(ss, 1); ss += __shfl_xor(ss, 2);
  ss += __shfl_xor(ss, 4); ss += __shfl_xor(ss, 8);
  float rinv = 1.f / fmaxf(sqrtf(ss), 1e-12f);
#pragma unroll
  for (int k = 0; k < 4; ++k) f[k] *= rinv;
  *(float4*)&(mod ? XTf : XVf)[(size_t)r * 64 + sl * 4] = *(float4*)f;
  *(uint2*)&XVT[(size_t)(NUSER + r) * 128 + mod * 64 + sl * 4] = f32_to_bf4(f);
}

// ---------------- routing (3 iters) + user GAT + egcn_h1(user) ----------------
__global__ __launch_bounds__(256) void routing_user_kernel(
    const float* __restrict__ pref_v, const float* __restrict__ pref_t,
    unsigned short* __restrict__ XVT, const unsigned short* __restrict__ X0b,
    const int* __restrict__ rp, const int* __restrict__ srcs,
    const float* __restrict__ conf,
    float* __restrict__ Ae, float* __restrict__ Be,
    float* __restrict__ SV, float* __restrict__ ST,
    float* __restrict__ wE, unsigned short* __restrict__ H1b,
    float* __restrict__ out) {
  __shared__ unsigned short cache[4][CAP * 128];
  __shared__ float estash[4][2 * ESTN];
  int wv = threadIdx.x >> 6;
  int u = blockIdx.x * 4 + wv;
  if (u >= NUSER) return;
  int lane = threadIdx.x & 63;
  int sub = lane >> 4, sl = lane & 15, half = sl >> 3, e8 = sl & 7;
  unsigned short* myc = cache[wv];
  float* es = estash[wv];

  const float* psrc = half ? pref_t : pref_v;
  float p[8];
  *(float4*)&p[0] = *(const float4*)&psrc[(size_t)u * 64 + e8 * 8];
  *(float4*)&p[4] = *(const float4*)&psrc[(size_t)u * 64 + e8 * 8 + 4];
  float ss = 0.f;
#pragma unroll
  for (int k = 0; k < 8; ++k) ss += p[k] * p[k];
  ss += __shfl_xor(ss, 1); ss += __shfl_xor(ss, 2); ss += __shfl_xor(ss, 4);
  float rinv = 1.f / fmaxf(sqrtf(ss), 1e-12f);
#pragma unroll
  for (int k = 0; k < 8; ++k) p[k] *= rinv;

  int jb = rp[u], je = rp[u + 1], deg = je - jb;

  for (int it = 0; it < 3; ++it) {
    float S = 0.f;
    float acc[8] = {0.f, 0.f, 0.f, 0.f, 0.f, 0.f, 0.f, 0.f};
    for (int i0 = 0; i0 < deg; i0 += 8) {
      int iA = i0 + sub, iB = i0 + 4 + sub;
      bool vA = iA < deg, vB = iB < deg;
      int jA = jb + (vA ? iA : 0), jB = jb + (vB ? iB : 0);
      uint4 uA, uB;
      if (it == 0) {
        int sA = srcs[jA], sB = srcs[jB];
        uA = *(const uint4*)&XVT[(size_t)sA * 128 + sl * 8];
        uB = *(const uint4*)&XVT[(size_t)sB * 128 + sl * 8];
        if (vA && iA < CAP) *(uint4*)&myc[iA * 128 + sl * 8] = uA;
        if (vB && iB < CAP) *(uint4*)&myc[iB * 128 + sl * 8] = uB;
      } else {
        int iiA = vA ? iA : 0, iiB = vB ? iB : 0;
        if (iiA < CAP) uA = *(const uint4*)&myc[iiA * 128 + sl * 8];
        else uA = *(const uint4*)&XVT[(size_t)srcs[jA] * 128 + sl * 8];
        if (iiB < CAP) uB = *(const uint4*)&myc[iiB * 128 + sl * 8];
        else uB = *(const uint4*)&XVT[(size_t)srcs[jB] * 128 + sl * 8];
      }
      float fA[8], fB[8];
      bf8_to_f32(uA, fA);
      bf8_to_f32(uB, fB);
      float dA = 0.f, dB = 0.f;
#pragma unroll
      for (int k = 0; k < 8; ++k) { dA += p[k] * fA[k]; dB += p[k] * fB[k]; }
      dA += __shfl_xor(dA, 1); dA += __shfl_xor(dA, 2); dA += __shfl_xor(dA, 4);
      dB += __shfl_xor(dB, 1); dB += __shfl_xor(dB, 2); dB += __shfl_xor(dB, 4);
      float eA = vA ? __expf(dA) : 0.f;
      float eB = vB ? __expf(dB) : 0.f;
      S += eA + eB;
#pragma unroll
      for (int k = 0; k < 8; ++k) acc[k] += eA * fA[k] + eB * fB[k];
    }
    S += __shfl_xor(S, 16); S += __shfl_xor(S, 32);
#pragma unroll
    for (int k = 0; k < 8; ++k) {
      acc[k] += __shfl_xor(acc[k], 16);
      acc[k] += __shfl_xor(acc[k], 32);
    }
    if (deg > 0) {
      float r = 1.f / S;
#pragma unroll
      for (int k = 0; k < 8; ++k) p[k] += acc[k] * r;
    }
    ss = 0.f;
#pragma unroll
    for (int k = 0; k < 8; ++k) ss += p[k] * p[k];
    ss += __shfl_xor(ss, 1); ss += __shfl_xor(ss, 2); ss += __shfl_xor(ss, 4);
    rinv = 1.f / fmaxf(sqrtf(ss), 1e-12f);
#pragma unroll
    for (int k = 0; k < 8; ++k) p[k] *= rinv;
  }

  // final GAT (user side)
  float S = 0.f;
  float acc[8] = {0.f, 0.f, 0.f, 0.f, 0.f, 0.f, 0.f, 0.f};
  for (int i0 = 0; i0 < deg; i0 += 8) {
    int iA = i0 + sub, iB = i0 + 4 + sub;
    bool vA = iA < deg, vB = iB < deg;
    int jA = jb + (vA ? iA : 0), jB = jb + (vB ? iB : 0);
    int sA = srcs[jA], sB = srcs[jB];
    int iiA = vA ? iA : 0, iiB = vB ? iB : 0;
    uint4 uA, uB;
    if (iiA < CAP) uA = *(const uint4*)&myc[iiA * 128 + sl * 8];
    else uA = *(const uint4*)&XVT[(size_t)sA * 128 + sl * 8];
    if (iiB < CAP) uB = *(const uint4*)&myc[iiB * 128 + sl * 8];
    else uB = *(const uint4*)&XVT[(size_t)sB * 128 + sl * 8];
    float fA[8], fB[8];
    bf8_to_f32(uA, fA);
    bf8_to_f32(uB, fB);
    float dA = 0.f, dB = 0.f;
#pragma unroll
    for (int k = 0; k < 8; ++k) { dA += p[k] * fA[k]; dB += p[k] * fB[k]; }
    dA += __shfl_xor(dA, 1); dA += __shfl_xor(dA, 2); dA += __shfl_xor(dA, 4);
    dB += __shfl_xor(dB, 1); dB += __shfl_xor(dB, 2); dB += __shfl_xor(dB, 4);
    float dAo = __shfl_xor(dA, 8), dBo = __shfl_xor(dB, 8);
    float eA = vA ? __expf(dA) : 0.f;
    float eB = vB ? __expf(dB) : 0.f;
    S += eA + eB;
#pragma unroll
    for (int k = 0; k < 8; ++k) acc[k] += eA * fA[k] + eB * fB[k];
    if (sl == 0) {
      if (vA) {
        float2 c = *(const float2*)&conf[2 * sA];
        float ae = eA * c.x, be = __expf(dAo) * c.y;
        Ae[jA] = ae; Be[jA] = be;
        if (iA < ESTN) { es[2 * iA] = ae; es[2 * iA + 1] = be; }
      }
      if (vB) {
        float2 c = *(const float2*)&conf[2 * sB];
        float ae = eB * c.x, be = __expf(dBo) * c.y;
        Ae[jB] = ae; Be[jB] = be;
        if (iB < ESTN) { es[2 * iB] = ae; es[2 * iB + 1] = be; }
      }
    }
  }
  S += __shfl_xor(S, 16); S += __shfl_xor(S, 32);
#pragma unroll
  for (int k = 0; k < 8; ++k) {
    acc[k] += __shfl_xor(acc[k], 16);
    acc[k] += __shfl_xor(acc[k], 32);
  }
  float So = __shfl_xor(S, 8);
  if (lane == 0) { SV[u] = S; ST[u] = So; }
  if (sub == 0) {
    float o[8];
    if (deg > 0) {
      float r = 1.f / S;
#pragma unroll
      for (int k = 0; k < 8; ++k) o[k] = p[k] + leaky(acc[k] * r);
    } else {
#pragma unroll
      for (int k = 0; k < 8; ++k) o[k] = p[k];
    }
    size_t ob = (size_t)u * 192 + 64 + half * 64 + e8 * 8;
    *(float4*)&out[ob] = *(float4*)&o[0];
    *(float4*)&out[ob + 4] = *(float4*)&o[4];
    *(uint4*)&XVT[(size_t)u * 128 + sl * 8] = f32_to_bf8(p);
  }

  // egcn_h1 for this user row
  float Sv = half ? So : S;
  float St_ = half ? S : So;
  float rv = (deg > 0) ? 0.5f / Sv : 0.f;
  float rt = (deg > 0) ? 0.5f / St_ : 0.f;
  float hacc[4] = {0.f, 0.f, 0.f, 0.f};
  for (int i0 = 0; i0 < deg; i0 += 8) {
    int iA = i0 + sub, iB = i0 + 4 + sub;
    bool vA = iA < deg, vB = iB < deg;
    int jA = jb + (vA ? iA : 0), jB = jb + (vB ? iB : 0);
    int sA = srcs[jA], sB = srcs[jB];
    uint2 gA = *(const uint2*)&X0b[(size_t)sA * 64 + sl * 4];
    uint2 gB = *(const uint2*)&X0b[(size_t)sB * 64 + sl * 4];
    int iiA = vA ? iA : 0, iiB = vB ? iB : 0;
    float aeA = (iiA < ESTN) ? es[2 * iiA] : Ae[jA];
    float beA = (iiA < ESTN) ? es[2 * iiA + 1] : Be[jA];
    float aeB = (iiB < ESTN) ? es[2 * iiB] : Ae[jB];
    float beB = (iiB < ESTN) ? es[2 * iiB + 1] : Be[jB];
    float wA = vA ? fmaxf(fmaxf(rv * aeA, rt * beA), 0.f) : 0.f;
    float wB = vB ? fmaxf(fmaxf(rv * aeB, rt * beB), 0.f) : 0.f;
    if (sl == 0) {
      if (vA) wE[jA] = wA;
      if (vB) wE[jB] = wB;
    }
    float fA[4], fB[4];
    bf4_to_f32(gA, fA);
    bf4_to_f32(gB, fB);
#pragma unroll
    for (int k = 0; k < 4; ++k) hacc[k] += wA * fA[k] + wB * fB[k];
  }
#pragma unroll
  for (int k = 0; k < 4; ++k) {
    hacc[k] += __shfl_xor(hacc[k], 16);
    hacc[k] += __shfl_xor(hacc[k], 32);
  }
  if (sub == 0) {
    float h[4] = {0.f, 0.f, 0.f, 0.f};
    if (deg > 0) {
      float r = 1.f / (float)deg;
#pragma unroll
      for (int k = 0; k < 4; ++k) h[k] = leaky(hacc[k] * r);
    }
    *(uint2*)&H1b[(size_t)u * 64 + sl * 4] = f32_to_bf4(h);
  }
}

// ---------------- item GAT + egcn_h1(item) ----------------
__global__ __launch_bounds__(256) void gat_item_kernel(
    const unsigned short* __restrict__ XVT, const unsigned short* __restrict__ X0b,
    const float* __restrict__ XVf, const float* __restrict__ XTf,
    const int* __restrict__ rp, const int* __restrict__ srcs,
    const float* __restrict__ conf,
    float* __restrict__ Ae, float* __restrict__ Be,
    float* __restrict__ SV, float* __restrict__ ST,
    float* __restrict__ wE, unsigned short* __restrict__ H1b,
    float* __restrict__ out) {
  __shared__ float estash[4][2 * ESTN];
  int wv = threadIdx.x >> 6;
  int wid = blockIdx.x * 4 + wv;
  if (wid >= NITEM) return;
  int lane = threadIdx.x & 63;
  int sub = lane >> 4, sl = lane & 15, half = sl >> 3, e8 = sl & 7;
  float* es = estash[wv];
  int row = NUSER + wid;
  const float* xsrc = half ? XTf : XVf;
  float xn[8];
  *(float4*)&xn[0] = *(const float4*)&xsrc[(size_t)wid * 64 + e8 * 8];
  *(float4*)&xn[4] = *(const float4*)&xsrc[(size_t)wid * 64 + e8 * 8 + 4];
  int jb = rp[row], je = rp[row + 1], deg = je - jb;
  float S = 0.f;
  float acc[8] = {0.f, 0.f, 0.f, 0.f, 0.f, 0.f, 0.f, 0.f};
  for (int i0 = 0; i0 < deg; i0 += 8) {
    int iA = i0 + sub, iB = i0 + 4 + sub;
    bool vA = iA < deg, vB = iB < deg;
    int jA = jb + (vA ? iA : 0), jB = jb + (vB ? iB : 0);
    int sA = srcs[jA], sB = srcs[jB];
    uint4 uA = *(const uint4*)&XVT[(size_t)sA * 128 + sl * 8];
    uint4 uB = *(const uint4*)&XVT[(size_t)sB * 128 + sl * 8];
    float fA[8], fB[8];
    bf8_to_f32(uA, fA);
    bf8_to_f32(uB, fB);
    float dA = 0.f, dB = 0.f;
#pragma unroll
    for (int k = 0; k < 8; ++k) { dA += xn[k] * fA[k]; dB += xn[k] * fB[k]; }
    dA += __shfl_xor(dA, 1); dA += __shfl_xor(dA, 2); dA += __shfl_xor(dA, 4);
    dB += __shfl_xor(dB, 1); dB += __shfl_xor(dB, 2); dB += __shfl_xor(dB, 4);
    float dAo = __shfl_xor(dA, 8), dBo = __shfl_xor(dB, 8);
    float eA = vA ? __expf(dA) : 0.f;
    float eB = vB ? __expf(dB) : 0.f;
    S += eA + eB;
#pragma unroll
    for (int k = 0; k < 8; ++k) acc[k] += eA * fA[k] + eB * fB[k];
    if (sl == 0) {
      if (vA) {
        float2 c = *(const float2*)&conf[2 * sA];
        float ae = eA * c.x, be = __expf(dAo) * c.y;
        Ae[jA] = ae; Be[jA] = be;
        if (iA < ESTN) { es[2 * iA] = ae; es[2 * iA + 1] = be; }
      }
      if (vB) {
        float2 c = *(const float2*)&conf[2 * sB];
        float ae = eB * c.x, be = __expf(dBo) * c.y;
        Ae[jB] = ae; Be[jB] = be;
        if (iB < ESTN) { es[2 * iB] = ae; es[2 * iB + 1] = be; }
      }
    }
  }
  S += __shfl_xor(S, 16); S += __shfl_xor(S, 32);
#pragma unroll
  for (int k = 0; k < 8; ++k) {
    acc[k] += __shfl_xor(acc[k], 16);
    acc[k] += __shfl_xor(acc[k], 32);
  }
  float So = __shfl_xor(S, 8);
  if (lane == 0) { SV[row] = S; ST[row] = So; }
  if (sub == 0) {
    float o[8];
    if (deg > 0) {
      float r = 1.f / S;
#pragma unroll
      for (int k = 0; k < 8; ++k) o[k] = xn[k] + leaky(acc[k] * r);
    } else {
#pragma unroll
      for (int k = 0; k < 8; ++k) o[k] = xn[k];
    }
    size_t ob = (size_t)row * 192 + 64 + half * 64 + e8 * 8;
    *(float4*)&out[ob] = *(float4*)&o[0];
    *(float4*)&out[ob + 4] = *(float4*)&o[4];
  }

  // egcn_h1 for this item row
  float Sv = half ? So : S;
  float St_ = half ? S : So;
  float rv = (deg > 0) ? 0.5f / Sv : 0.f;
  float rt = (deg > 0) ? 0.5f / St_ : 0.f;
  float hacc[4] = {0.f, 0.f, 0.f, 0.f};
  for (int i0 = 0; i0 < deg; i0 += 8) {
    int iA = i0 + sub, iB = i0 + 4 + sub;
    bool vA = iA < deg, vB = iB < deg;
    int jA = jb + (vA ? iA : 0), jB = jb + (vB ? iB : 0);
    int sA = srcs[jA], sB = srcs[jB];
    uint2 gA = *(const uint2*)&X0b[(size_t)sA * 64 + sl * 4];
    uint2 gB = *(const uint2*)&X0b[(size_t)sB * 64 + sl * 4];
    int iiA = vA ? iA : 0, iiB = vB ? iB : 0;
    float aeA = (iiA < ESTN) ? es[2 * iiA] : Ae[jA];
    float beA = (iiA < ESTN) ? es[2 * iiA + 1] : Be[jA];
    float aeB = (iiB < ESTN) ? es[2 * iiB] : Ae[jB];
    float beB = (iiB < ESTN) ? es[2 * iiB + 1] : Be[jB];
    float wA = vA ? fmaxf(fmaxf(rv * aeA, rt * beA), 0.f) : 0.f;
    float wB = vB ? fmaxf(fmaxf(rv * aeB, rt * beB), 0.f) : 0.f;
    if (sl == 0) {
      if (vA) wE[jA] = wA;
      if (vB) wE[jB] = wB;
    }
    float fA[4], fB[4];
    bf4_to_f32(gA, fA);
    bf4_to_f32(gB, fB);
#pragma unroll
    for (int k = 0; k < 4; ++k) hacc[k] += wA * fA[k] + wB * fB[k];
  }
#pragma unroll
  for (int k = 0; k < 4; ++k) {
    hacc[k] += __shfl_xor(hacc[k], 16);
    hacc[k] += __shfl_xor(hacc[k], 32);
  }
  if (sub == 0) {
    float h[4] = {0.f, 0.f, 0.f, 0.f};
    if (deg > 0) {
      float r = 1.f / (float)deg;
#pragma unroll
      for (int k = 0; k < 4; ++k) h[k] = leaky(hacc[k] * r);
    }
    *(uint2*)&H1b[(size_t)row * 64 + sl * 4] = f32_to_bf4(h);
  }
}

// ---------------- egcn hop 2 + id_rep write ----------------
__global__ __launch_bounds__(256) void egcn_h2_kernel(
    const float* __restrict__ x0, const unsigned short* __restrict__ H1b,
    const int* __restrict__ rp, const int* __restrict__ srcs,
    const float* __restrict__ wE, float* __restrict__ out) {
  int wid = (blockIdx.x * 256 + threadIdx.x) >> 6;
  if (wid >= NNODE) return;
  int lane = threadIdx.x & 63, sub = lane >> 4, sl = lane & 15;
  int jb = rp[wid], je = rp[wid + 1], deg = je - jb;
  float acc[4] = {0.f, 0.f, 0.f, 0.f};
  for (int i0 = 0; i0 < deg; i0 += 8) {
    int iA = i0 + sub, iB = i0 + 4 + sub;
    bool vA = iA < deg, vB = iB < deg;
    int jA = jb + (vA ? iA : 0), jB = jb + (vB ? iB : 0);
    int sA = srcs[jA], sB = srcs[jB];
    float wA = vA ? wE[jA] : 0.f;
    float wB = vB ? wE[jB] : 0.f;
    uint2 gA = *(const uint2*)&H1b[(size_t)sA * 64 + sl * 4];
    uint2 gB = *(const uint2*)&H1b[(size_t)sB * 64 + sl * 4];
    float fA[4], fB[4];
    bf4_to_f32(gA, fA);
    bf4_to_f32(gB, fB);
#pragma unroll
    for (int k = 0; k < 4; ++k) acc[k] += wA * fA[k] + wB * fB[k];
  }
#pragma unroll
  for (int k = 0; k < 4; ++k) {
    acc[k] += __shfl_xor(acc[k], 16);
    acc[k] += __shfl_xor(acc[k], 32);
  }
  if (sub == 0) {
    float h2[4] = {0.f, 0.f, 0.f, 0.f};
    if (deg > 0) {
      float r = 1.f / (float)deg;
#pragma unroll
      for (int k = 0; k < 4; ++k) h2[k] = leaky(acc[k] * r);
    }
    float4 a = *(const float4*)&x0[(size_t)wid * 64 + sl * 4];
    uint2 u2 = *(const uint2*)&H1b[(size_t)wid * 64 + sl * 4];
    float h1[4];
    bf4_to_f32(u2, h1);
    float4 o = {a.x + h1[0] + h2[0], a.y + h1[1] + h2[1],
                a.z + h1[2] + h2[2], a.w + h1[3] + h2[3]};
    *(float4*)&out[(size_t)wid * 192 + sl * 4] = o;
  }
}

// ---------------- launcher ----------------
extern "C" void kernel_launch(void* const* d_in, const int* in_sizes, int n_in,
                              void* d_out, int out_size, void* d_ws, size_t ws_size,
                              hipStream_t stream) {
  const int* ei = (const int*)d_in[0];
  const float* v_feat = (const float*)d_in[1];
  const float* t_feat = (const float*)d_in[2];
  const float* pref_v = (const float*)d_in[3];
  const float* pref_t = (const float*)d_in[4];
  const float* W_v = (const float*)d_in[5];
  const float* b_v = (const float*)d_in[6];
  const float* W_t = (const float*)d_in[7];
  const float* b_t = (const float*)d_in[8];
  const float* id_emb = (const float*)d_in[9];
  const float* conf = (const float*)d_in[10];
  float* out = (float*)d_out;

  float* ws = (float*)d_ws;
  unsigned short* XVT = (unsigned short*)(ws + O_XVT);
  float* x0 = ws + O_X0;
  unsigned short* X0b = (unsigned short*)(ws + O_X0B);
  unsigned short* H1b = (unsigned short*)(ws + O_H1B);
  float* XVf = ws + O_XVF;
  float* XTf = ws + O_XTF;
  float* Ae = ws + O_AE;
  float* Be = ws + O_BE;
  float* wE = ws + O_WE;
  float* SV = ws + O_SV;
  float* ST = ws + O_ST;
  int* deg = (int*)(ws + O_DEG);
  int* row_ptr = (int*)(ws + O_RP);
  int* fill = (int*)(ws + O_FILL);
  int* srcs = (int*)(ws + O_SRC);
  int* bsum = (int*)(ws + O_BSUM);
  short* wsp = (short*)(ws + O_WSPL);
  float* Pv = ws + O_PV;
  float* Pt = ws + O_PT;

  const int NB = (NNODE + 255) / 256;  // 352

  hipMemsetAsync(deg, 0, NNODE * sizeof(int), stream);
  wsplit_all_kernel<<<(2048 * 64 + 384 * 64 + 255) / 256, 256, 0, stream>>>(W_v, W_t, wsp);
  mega_prep_kernel<<<MEGA_BLOCKS, 256, 0, stream>>>(v_feat, t_feat, wsp, ei, deg,
                                                    id_emb, x0, X0b, Pv, Pt);
  scan_a_kernel<<<NB, 256, 0, stream>>>(deg, bsum);
  scan_b_kernel<<<NB, 256, 0, stream>>>(deg, bsum, row_ptr, fill);
  fill_epi_kernel<<<FE_FILL + 5000, 256, 0, stream>>>(ei, fill, srcs, Pv, Pt, b_v, b_t,
                                                      XVf, XTf, XVT);
  routing_user_kernel<<<NUSER / 4, 256, 0, stream>>>(pref_v, pref_t, XVT, X0b, row_ptr,
                                                     srcs, conf, Ae, Be, SV, ST, wE, H1b, out);
  gat_item_kernel<<<NITEM / 4, 256, 0, stream>>>(XVT, X0b, XVf, XTf, row_ptr, srcs, conf,
                                                 Ae, Be, SV, ST, wE, H1b, out);
  egcn_h2_kernel<<<NNODE / 4, 256, 0, stream>>>(x0, H1b, row_ptr, srcs, wE, out);
}